// Round 14
// baseline (169.820 us; speedup 1.0000x reference)
//
#include <hip/hip_runtime.h>

#define NN   50000
#define NE   1000000
#define FIN  128
#define HID  64
#define HEADS 4
#define C1   256          // HEADS*HID
#define NG   512
#define ETOT (NE + NN)    // edges + self-loops
#define BSH  10           // bucket = dst >> 10 (1024 nodes/bucket)
#define NBUK 49           // ceil(NN/1024)
#define CHUNK 8192
#define NCHUNK 123        // ceil(NE/CHUNK)
#define NPREP 192         // (FIN*C1 + C1*HID)/256
#define NHIST 64
#define NGEMM1 782        // ceil(ceil(NN/16)/4) row-tile groups (x2 ch blocks)

typedef __attribute__((ext_vector_type(8))) short bf16x8;
typedef __attribute__((ext_vector_type(4))) float f32x4;
typedef __attribute__((ext_vector_type(2))) float f32x2;

__device__ __forceinline__ float lrelu(float v) { return v > 0.f ? v : 0.2f * v; }
__device__ __forceinline__ float eluf(float v)  { return v > 0.f ? v : __expf(v) - 1.f; }

__device__ __forceinline__ unsigned short f2bf(float f) {
    unsigned u = __float_as_uint(f);
    unsigned r = (u + 0x7FFFu + ((u >> 16) & 1u)) >> 16;
    return (unsigned short)r;
}
__device__ __forceinline__ float bf2f(unsigned short b) {
    return __uint_as_float(((unsigned)b) << 16);
}
__device__ __forceinline__ unsigned char f2fp8(float f) {
    int w = __builtin_amdgcn_cvt_pk_fp8_f32(f, f, 0, false);
    return (unsigned char)(w & 0xFF);
}

// ---------------- fused setup: weight prep + partial hist + gstart + bcur zero ----------------
__global__ __launch_bounds__(256) void k_setup(const float* __restrict__ W1,
                                               const float* __restrict__ W2,
                                               const int* __restrict__ dst,
                                               const int* __restrict__ batch,
                                               unsigned short* __restrict__ W1t,
                                               unsigned short* __restrict__ W2t,
                                               int* __restrict__ bhistp,
                                               int* __restrict__ bcur,
                                               int* __restrict__ offs,
                                               int* __restrict__ gstart) {
    int b = blockIdx.x;
    int tid = threadIdx.x;
    if (b < NPREP) {
        int i = b * 256 + tid;
        if (i < FIN * C1) {
            int k = i / C1, c = i % C1;
            W1t[c * FIN + k] = f2bf(W1[i]);
        } else {
            int j = i - FIN * C1;
            if (j < C1 * HID) {
                int k = j / HID, c = j % HID;
                W2t[c * C1 + k] = f2bf(W2[j]);
            }
        }
    } else if (b < NPREP + NHIST) {
        __shared__ int lh[NBUK];
        if (tid < NBUK) lh[tid] = 0;
        __syncthreads();
        for (int e = (b - NPREP) * 256 + tid; e < NE; e += NHIST * 256)
            atomicAdd(&lh[dst[e] >> BSH], 1);
        __syncthreads();
        if (tid < NBUK) bhistp[(b - NPREP) * NBUK + tid] = lh[tid];   // partials, no global atomics
    } else {
        if (tid < NBUK) bcur[tid] = 0;
        if (tid == 64) offs[NN] = ETOT;
        for (int g = tid; g <= NG; g += 256) {
            int lo = 0, hi = NN;
            while (lo < hi) {
                int mid = (lo + hi) >> 1;
                if (batch[mid] < g) lo = mid + 1; else hi = mid;
            }
            gstart[g] = lo;
        }
    }
}

// ---------------- FUSED: edge partition (blocks 0..NCHUNK) + gemm1 ch-split (rest) ----------------
__global__ __launch_bounds__(256) void k_part_gemm1(const int* __restrict__ srcA,
                                                    const int* __restrict__ dstA,
                                                    const int* __restrict__ bhistp,
                                                    int* __restrict__ bcur,
                                                    int* __restrict__ ebuf,
                                                    const float* __restrict__ x,
                                                    const unsigned short* __restrict__ W1t,
                                                    const float* __restrict__ asrc,
                                                    const float* __restrict__ adst,
                                                    unsigned char* __restrict__ h1f,
                                                    float* __restrict__ es1,
                                                    float* __restrict__ ed1) {
    __shared__ int lsh[128 * FIN / 2];   // 32 KB, reused by both roles
    int tid = threadIdx.x;

    if (blockIdx.x < NCHUNK) {
        // ---- partition role ----
        int* lcnt  = lsh;
        int* gbase = lsh + NBUK;
        int* lrank = lsh + 2 * NBUK;
        int* ssum  = lsh + 3 * NBUK;
        int* sbase = lsh + 4 * NBUK;
        if (tid < NBUK) {
            int s = 0;
            #pragma unroll 8
            for (int j = 0; j < NHIST; ++j) s += bhistp[j * NBUK + tid];
            ssum[tid] = s;
        }
        if (tid < NBUK) { lcnt[tid] = 0; lrank[tid] = 0; }
        __syncthreads();
        if (tid < 64) {
            int v = (tid < NBUK) ? ssum[tid] : 0;
            int xs = v;
            #pragma unroll
            for (int off = 1; off < 64; off <<= 1) {
                int t = __shfl_up(xs, off);
                if (tid >= off) xs += t;
            }
            if (tid < NBUK) sbase[tid] = xs - v;   // exclusive
        }
        __syncthreads();
        int e0 = blockIdx.x * CHUNK;
        int e1 = min(e0 + CHUNK, NE);
        for (int e = e0 + tid; e < e1; e += 256)
            atomicAdd(&lcnt[dstA[e] >> BSH], 1);
        __syncthreads();
        if (tid < NBUK) gbase[tid] = sbase[tid] + atomicAdd(&bcur[tid], lcnt[tid]);
        __syncthreads();
        for (int e = e0 + tid; e < e1; e += 256) {
            int d = dstA[e];
            int b = d >> BSH;
            int r = atomicAdd(&lrank[b], 1);
            ebuf[gbase[b] + r] = ((d & 1023) << 17) | srcA[e];
        }
        return;
    }

    // ---- gemm1 role: one block = one (row-tile-group, ch) pair ----
    unsigned short* Wl = (unsigned short*)lsh;
    int g1 = blockIdx.x - NCHUNK;
    int rt = g1 >> 1;
    int ch = g1 & 1;          // column half: cols [ch*128, ch*128+128)
    int lane = tid & 63, wv = tid >> 6;
    int r0 = (rt * 4 + wv) * 16;
    int g = lane >> 4, q = lane & 15;

    int ar = min(r0 + q, NN - 1);
    const float* xr = x + (size_t)ar * FIN;
    bf16x8 afr[4];
    #pragma unroll
    for (int kt = 0; kt < 4; ++kt) {
        float4 u0 = *(const float4*)(xr + kt * 32 + g * 8);
        float4 u1 = *(const float4*)(xr + kt * 32 + g * 8 + 4);
        bf16x8 a;
        a[0] = (short)f2bf(u0.x); a[1] = (short)f2bf(u0.y);
        a[2] = (short)f2bf(u0.z); a[3] = (short)f2bf(u0.w);
        a[4] = (short)f2bf(u1.x); a[5] = (short)f2bf(u1.y);
        a[6] = (short)f2bf(u1.z); a[7] = (short)f2bf(u1.w);
        afr[kt] = a;
    }

    // stage this ch's 128 cols of W1t (32 KB), swizzled
    const uint4* src = (const uint4*)(W1t + (size_t)ch * 128 * FIN);
    #pragma unroll
    for (int i = 0; i < 8; ++i) {
        int idx = tid + i * 256;
        uint4 v = src[idx];
        unsigned byte = (unsigned)idx << 4;
        unsigned dst = byte ^ (((byte >> 8) & 7) << 4);
        *(uint4*)((char*)Wl + dst) = v;
    }
    __syncthreads();

    #pragma unroll
    for (int hh = 0; hh < 2; ++hh) {
        int h = ch * 2 + hh;
        float ps[4] = {0.f, 0.f, 0.f, 0.f};
        float pd[4] = {0.f, 0.f, 0.f, 0.f};
        #pragma unroll
        for (int tl = 0; tl < 4; ++tl) {
            int col = (h * 4 + tl) * 16 + q;
            int cl = col - ch * 128;
            f32x4 acc = {0.f, 0.f, 0.f, 0.f};
            #pragma unroll
            for (int kt = 0; kt < 4; ++kt) {
                unsigned bb = (unsigned)cl * 256 + kt * 64 + g * 16;
                bf16x8 b = *(const bf16x8*)((const char*)Wl + (bb ^ (((unsigned)cl & 7) << 4)));
                acc = __builtin_amdgcn_mfma_f32_16x16x32_bf16(afr[kt], b, acc, 0, 0, 0);
            }
            float av = asrc[col], bv = adst[col];
            #pragma unroll
            for (int j = 0; j < 4; ++j) {
                int rr = min(r0 + g * 4 + j, NN - 1);
                h1f[(size_t)rr * C1 + col] = f2fp8(acc[j]);
                ps[j] += acc[j] * av;
                pd[j] += acc[j] * bv;
            }
        }
        #pragma unroll
        for (int j = 0; j < 4; ++j) {
            #pragma unroll
            for (int off = 1; off < 16; off <<= 1) {
                ps[j] += __shfl_xor(ps[j], off);
                pd[j] += __shfl_xor(pd[j], off);
            }
            if (q == 0) {
                int rr = min(r0 + g * 4 + j, NN - 1);
                es1[rr * 4 + h] = ps[j];
                ed1[rr * 4 + h] = pd[j];
            }
        }
    }
}

// per-bucket: local degrees -> scan -> offs + colsrc fill (all XCD-local)
__global__ __launch_bounds__(1024) void k_bfill(const int* __restrict__ ebuf,
                                                const int* __restrict__ bhistp,
                                                int* __restrict__ offs,
                                                int* __restrict__ colsrc) {
    __shared__ int ldeg[1024];
    __shared__ int lcur[1024];
    __shared__ int ws[16];
    __shared__ int ssum[NBUK];
    __shared__ int sbase[NBUK];
    int b = blockIdx.x;
    int tid = threadIdx.x;
    int nbase = b << BSH;
    int ncnt = min(1024, NN - nbase);
    if (tid < NBUK) {
        int s = 0;
        #pragma unroll 8
        for (int j = 0; j < NHIST; ++j) s += bhistp[j * NBUK + tid];
        ssum[tid] = s;
    }
    ldeg[tid] = 0;
    __syncthreads();
    if (tid < 64) {
        int v = (tid < NBUK) ? ssum[tid] : 0;
        int xs = v;
        #pragma unroll
        for (int off = 1; off < 64; off <<= 1) {
            int t = __shfl_up(xs, off);
            if (tid >= off) xs += t;
        }
        if (tid < NBUK) sbase[tid] = xs - v;   // exclusive
    }
    __syncthreads();
    int ebeg = sbase[b], eend = sbase[b] + ssum[b];
    for (int i = ebeg + tid; i < eend; i += 1024)
        atomicAdd(&ldeg[ebuf[i] >> 17], 1);
    __syncthreads();
    int v = (tid < ncnt) ? ldeg[tid] + 1 : 0;
    int lane = tid & 63, wv = tid >> 6;
    int x = v;
    #pragma unroll
    for (int off = 1; off < 64; off <<= 1) {
        int t = __shfl_up(x, off);
        if (lane >= off) x += t;
    }
    if (lane == 63) ws[wv] = x;
    __syncthreads();
    if (tid < 16) {
        int y = ws[tid];
        #pragma unroll
        for (int off = 1; off < 16; off <<= 1) {
            int t = __shfl_up(y, off);
            if (tid >= off) y += t;
        }
        ws[tid] = y;
    }
    __syncthreads();
    int base = wv ? ws[wv - 1] : 0;
    int excl = base + x - v;
    int gofs = ebeg + nbase + excl;
    if (tid < ncnt) {
        offs[nbase + tid] = gofs;
        lcur[tid] = gofs;
    }
    __syncthreads();
    for (int i = ebeg + tid; i < eend; i += 1024) {
        int pe = ebuf[i];
        int p = atomicAdd(&lcur[pe >> 17], 1);
        colsrc[p] = pe & 0x1FFFF;
    }
    __syncthreads();
    if (tid < ncnt) colsrc[lcur[tid]] = nbase + tid;   // self-loop at segment end
}

// ---------------- Layer 1 aggregation: fp8 gathers, 4-load interleave ----------------
__global__ __launch_bounds__(512) void k_agg1(const int* __restrict__ offs,
                                              const int* __restrict__ colsrc,
                                              const unsigned char* __restrict__ h1f,
                                              const float* __restrict__ es1,
                                              const float* __restrict__ ed1,
                                              const float* __restrict__ b1,
                                              unsigned short* __restrict__ h1p) {
    __shared__ int   sls[8][64];
    __shared__ float sla[8][64][4];
    int lane = threadIdx.x & 63, wv = threadIdx.x >> 6;
    int n = blockIdx.x * 8 + wv;
    if (n >= NN) return;
    int beg = offs[n], end = offs[n + 1], deg = end - beg;
    float4 edv = *(const float4*)(ed1 + n * 4);
    int half = lane >> 5, q5 = lane & 31;
    int hd = q5 >> 3;
    f32x2 acc2[4];
    #pragma unroll
    for (int j = 0; j < 4; ++j) acc2[j] = (f32x2){0.f, 0.f};

    if (deg <= 64) {
        int msrc = 0;
        float m0 = 0.f, m1 = 0.f, m2 = 0.f, m3 = 0.f;
        if (lane < deg) {
            msrc = colsrc[beg + lane];
            float4 ev = *(const float4*)(es1 + msrc * 4);
            m0 = __expf(lrelu(ev.x + edv.x));
            m1 = __expf(lrelu(ev.y + edv.y));
            m2 = __expf(lrelu(ev.z + edv.z));
            m3 = __expf(lrelu(ev.w + edv.w));
        }
        float s0 = m0, s1 = m1, s2 = m2, s3 = m3;
        #pragma unroll
        for (int off = 1; off < 64; off <<= 1) {
            s0 += __shfl_xor(s0, off);
            s1 += __shfl_xor(s1, off);
            s2 += __shfl_xor(s2, off);
            s3 += __shfl_xor(s3, off);
        }
        sls[wv][lane] = msrc;
        sla[wv][lane][0] = m0 * (1.f / s0);
        sla[wv][lane][1] = m1 * (1.f / s1);
        sla[wv][lane][2] = m2 * (1.f / s2);
        sla[wv][lane][3] = m3 * (1.f / s3);

        for (int i = 0; i < deg; i += 8) {
            int e0 = (i + half) & 63, e1 = (i + 2 + half) & 63, e2 = (i + 4 + half) & 63, e3 = (i + 6 + half) & 63;
            int   s0i = sls[wv][e0], s1i = sls[wv][e1], s2i = sls[wv][e2], s3i = sls[wv][e3];
            f32x2 a0 = (f32x2){sla[wv][e0][hd], sla[wv][e0][hd]};
            f32x2 a1 = (f32x2){sla[wv][e1][hd], sla[wv][e1][hd]};
            f32x2 a2 = (f32x2){sla[wv][e2][hd], sla[wv][e2][hd]};
            f32x2 a3 = (f32x2){sla[wv][e3][hd], sla[wv][e3][hd]};
            uint2 h0 = *(const uint2*)(h1f + (size_t)s0i * C1 + q5 * 8);
            uint2 h1 = *(const uint2*)(h1f + (size_t)s1i * C1 + q5 * 8);
            uint2 h2 = *(const uint2*)(h1f + (size_t)s2i * C1 + q5 * 8);
            uint2 h3 = *(const uint2*)(h1f + (size_t)s3i * C1 + q5 * 8);
            f32x2 p;
            p = __builtin_amdgcn_cvt_pk_f32_fp8(h0.x, false); acc2[0] += p * a0;
            p = __builtin_amdgcn_cvt_pk_f32_fp8(h0.x, true);  acc2[1] += p * a0;
            p = __builtin_amdgcn_cvt_pk_f32_fp8(h0.y, false); acc2[2] += p * a0;
            p = __builtin_amdgcn_cvt_pk_f32_fp8(h0.y, true);  acc2[3] += p * a0;
            p = __builtin_amdgcn_cvt_pk_f32_fp8(h1.x, false); acc2[0] += p * a1;
            p = __builtin_amdgcn_cvt_pk_f32_fp8(h1.x, true);  acc2[1] += p * a1;
            p = __builtin_amdgcn_cvt_pk_f32_fp8(h1.y, false); acc2[2] += p * a1;
            p = __builtin_amdgcn_cvt_pk_f32_fp8(h1.y, true);  acc2[3] += p * a1;
            p = __builtin_amdgcn_cvt_pk_f32_fp8(h2.x, false); acc2[0] += p * a2;
            p = __builtin_amdgcn_cvt_pk_f32_fp8(h2.x, true);  acc2[1] += p * a2;
            p = __builtin_amdgcn_cvt_pk_f32_fp8(h2.y, false); acc2[2] += p * a2;
            p = __builtin_amdgcn_cvt_pk_f32_fp8(h2.y, true);  acc2[3] += p * a2;
            p = __builtin_amdgcn_cvt_pk_f32_fp8(h3.x, false); acc2[0] += p * a3;
            p = __builtin_amdgcn_cvt_pk_f32_fp8(h3.x, true);  acc2[1] += p * a3;
            p = __builtin_amdgcn_cvt_pk_f32_fp8(h3.y, false); acc2[2] += p * a3;
            p = __builtin_amdgcn_cvt_pk_f32_fp8(h3.y, true);  acc2[3] += p * a3;
        }
    } else {
        float s0 = 0.f, s1 = 0.f, s2 = 0.f, s3 = 0.f;
        for (int i = beg + lane; i < end; i += 64) {
            int s = colsrc[i];
            float4 ev = *(const float4*)(es1 + s * 4);
            s0 += __expf(lrelu(ev.x + edv.x));
            s1 += __expf(lrelu(ev.y + edv.y));
            s2 += __expf(lrelu(ev.z + edv.z));
            s3 += __expf(lrelu(ev.w + edv.w));
        }
        #pragma unroll
        for (int off = 1; off < 64; off <<= 1) {
            s0 += __shfl_xor(s0, off);
            s1 += __shfl_xor(s1, off);
            s2 += __shfl_xor(s2, off);
            s3 += __shfl_xor(s3, off);
        }
        float rr = hd == 0 ? 1.f / s0 : hd == 1 ? 1.f / s1 : hd == 2 ? 1.f / s2 : 1.f / s3;
        float ed_h = hd == 0 ? edv.x : hd == 1 ? edv.y : hd == 2 ? edv.z : edv.w;
        for (int i = beg; i < end; i += 2) {
            int idx = i + half;
            if (idx < end) {
                int s = colsrc[idx];
                float eh = es1[s * 4 + hd] + ed_h;
                float av = __expf(lrelu(eh)) * rr;
                f32x2 a = (f32x2){av, av};
                uint2 hv = *(const uint2*)(h1f + (size_t)s * C1 + q5 * 8);
                f32x2 p;
                p = __builtin_amdgcn_cvt_pk_f32_fp8(hv.x, false); acc2[0] += p * a;
                p = __builtin_amdgcn_cvt_pk_f32_fp8(hv.x, true);  acc2[1] += p * a;
                p = __builtin_amdgcn_cvt_pk_f32_fp8(hv.y, false); acc2[2] += p * a;
                p = __builtin_amdgcn_cvt_pk_f32_fp8(hv.y, true);  acc2[3] += p * a;
            }
        }
    }

    float acc[8];
    #pragma unroll
    for (int j = 0; j < 4; ++j) { acc[2*j] = acc2[j][0]; acc[2*j+1] = acc2[j][1]; }
    #pragma unroll
    for (int j = 0; j < 8; ++j) acc[j] += __shfl_xor(acc[j], 32);

    if (half == 0) {
        float4 bv0 = *(const float4*)(b1 + q5 * 8);
        float4 bv1 = *(const float4*)(b1 + q5 * 8 + 4);
        bf16x8 o;
        o[0] = (short)f2bf(eluf(acc[0] + bv0.x));
        o[1] = (short)f2bf(eluf(acc[1] + bv0.y));
        o[2] = (short)f2bf(eluf(acc[2] + bv0.z));
        o[3] = (short)f2bf(eluf(acc[3] + bv0.w));
        o[4] = (short)f2bf(eluf(acc[4] + bv1.x));
        o[5] = (short)f2bf(eluf(acc[5] + bv1.y));
        o[6] = (short)f2bf(eluf(acc[6] + bv1.z));
        o[7] = (short)f2bf(eluf(acc[7] + bv1.w));
        *(bf16x8*)(h1p + (size_t)n * C1 + q5 * 8) = o;
    }
}

// ---------------- Layer 2 GEMM (MFMA bf16, LDS-staged W, fp8 h2 output) ----------------
__global__ __launch_bounds__(256) void k_gemm2(const unsigned short* __restrict__ h1p,
                                               const unsigned short* __restrict__ W2t,
                                               const float* __restrict__ as2,
                                               const float* __restrict__ ad2,
                                               unsigned char* __restrict__ h2f,
                                               float* __restrict__ es2,
                                               float* __restrict__ ed2) {
    __shared__ unsigned short Wl[HID * C1];   // 32 KB
    int tid = threadIdx.x;
    int lane = tid & 63, wv = tid >> 6;
    int r0 = (blockIdx.x * 4 + wv) * 16;
    int g = lane >> 4, q = lane & 15;

    const uint4* src = (const uint4*)W2t;
    #pragma unroll
    for (int i = 0; i < 8; ++i) {
        int idx = tid + i * 256;
        uint4 v = src[idx];
        unsigned byte = (unsigned)idx << 4;
        unsigned dst = byte ^ (((byte >> 9) & 7) << 4);
        *(uint4*)((char*)Wl + dst) = v;
    }

    int ar = min(r0 + q, NN - 1);
    const unsigned short* arp = h1p + (size_t)ar * C1;
    bf16x8 afr[8];
    #pragma unroll
    for (int kt = 0; kt < 8; ++kt)
        afr[kt] = *(const bf16x8*)(arp + kt * 32 + g * 8);

    __syncthreads();

    float ps[4] = {0.f, 0.f, 0.f, 0.f};
    float pd[4] = {0.f, 0.f, 0.f, 0.f};
    #pragma unroll
    for (int t = 0; t < 4; ++t) {
        int col = t * 16 + q;
        f32x4 acc = {0.f, 0.f, 0.f, 0.f};
        #pragma unroll
        for (int kt = 0; kt < 8; ++kt) {
            unsigned bb = (unsigned)col * 512 + kt * 64 + g * 16;
            bf16x8 b = *(const bf16x8*)((const char*)Wl + (bb ^ (((unsigned)col & 7) << 4)));
            acc = __builtin_amdgcn_mfma_f32_16x16x32_bf16(afr[kt], b, acc, 0, 0, 0);
        }
        float av = as2[col], bv = ad2[col];
        #pragma unroll
        for (int j = 0; j < 4; ++j) {
            int rr = min(r0 + g * 4 + j, NN - 1);
            h2f[(size_t)rr * HID + col] = f2fp8(acc[j]);
            ps[j] += acc[j] * av;
            pd[j] += acc[j] * bv;
        }
    }
    #pragma unroll
    for (int j = 0; j < 4; ++j) {
        #pragma unroll
        for (int off = 1; off < 16; off <<= 1) {
            ps[j] += __shfl_xor(ps[j], off);
            pd[j] += __shfl_xor(pd[j], off);
        }
        if (q == 0) {
            int rr = min(r0 + g * 4 + j, NN - 1);
            es2[rr] = ps[j];
            ed2[rr] = pd[j];
        }
    }
}

// ---------------- Layer 2 aggregation: fp8 gathers, 4-load interleave, bf16 h3 ----------------
__global__ __launch_bounds__(512) void k_agg2(const int* __restrict__ offs,
                                              const int* __restrict__ colsrc,
                                              const unsigned char* __restrict__ h2f,
                                              const float* __restrict__ es2,
                                              const float* __restrict__ ed2,
                                              const float* __restrict__ b2,
                                              unsigned short* __restrict__ h3) {
    __shared__ int   sls[8][64];
    __shared__ float sla[8][64];
    int lane = threadIdx.x & 63, wv = threadIdx.x >> 6;
    int n = blockIdx.x * 8 + wv;
    if (n >= NN) return;
    int beg = offs[n], end = offs[n + 1], deg = end - beg;
    float edv = ed2[n];
    int g = lane >> 4, q = lane & 15;
    f32x2 acc2[2];
    acc2[0] = (f32x2){0.f, 0.f};
    acc2[1] = (f32x2){0.f, 0.f};

    if (deg <= 64) {
        int msrc = 0;
        float mex = 0.f;
        if (lane < deg) {
            msrc = colsrc[beg + lane];
            mex = __expf(lrelu(es2[msrc] + edv));
        }
        float ss = mex;
        #pragma unroll
        for (int off = 1; off < 64; off <<= 1) ss += __shfl_xor(ss, off);
        sls[wv][lane] = msrc;
        sla[wv][lane] = mex * (1.f / ss);

        for (int i = 0; i < deg; i += 16) {
            int e0 = (i + g) & 63, e1 = (i + 4 + g) & 63, e2 = (i + 8 + g) & 63, e3 = (i + 12 + g) & 63;
            int   s0i = sls[wv][e0], s1i = sls[wv][e1], s2i = sls[wv][e2], s3i = sls[wv][e3];
            f32x2 a0 = (f32x2){sla[wv][e0], sla[wv][e0]};
            f32x2 a1 = (f32x2){sla[wv][e1], sla[wv][e1]};
            f32x2 a2 = (f32x2){sla[wv][e2], sla[wv][e2]};
            f32x2 a3 = (f32x2){sla[wv][e3], sla[wv][e3]};
            unsigned w0 = *(const unsigned*)(h2f + (size_t)s0i * HID + q * 4);
            unsigned w1 = *(const unsigned*)(h2f + (size_t)s1i * HID + q * 4);
            unsigned w2 = *(const unsigned*)(h2f + (size_t)s2i * HID + q * 4);
            unsigned w3 = *(const unsigned*)(h2f + (size_t)s3i * HID + q * 4);
            f32x2 p;
            p = __builtin_amdgcn_cvt_pk_f32_fp8(w0, false); acc2[0] += p * a0;
            p = __builtin_amdgcn_cvt_pk_f32_fp8(w0, true);  acc2[1] += p * a0;
            p = __builtin_amdgcn_cvt_pk_f32_fp8(w1, false); acc2[0] += p * a1;
            p = __builtin_amdgcn_cvt_pk_f32_fp8(w1, true);  acc2[1] += p * a1;
            p = __builtin_amdgcn_cvt_pk_f32_fp8(w2, false); acc2[0] += p * a2;
            p = __builtin_amdgcn_cvt_pk_f32_fp8(w2, true);  acc2[1] += p * a2;
            p = __builtin_amdgcn_cvt_pk_f32_fp8(w3, false); acc2[0] += p * a3;
            p = __builtin_amdgcn_cvt_pk_f32_fp8(w3, true);  acc2[1] += p * a3;
        }
    } else {
        float ss = 0.f;
        for (int i = beg + lane; i < end; i += 64) {
            int s = colsrc[i];
            ss += __expf(lrelu(es2[s] + edv));
        }
        #pragma unroll
        for (int off = 1; off < 64; off <<= 1) ss += __shfl_xor(ss, off);
        float rs = 1.f / ss;
        for (int i = beg; i < end; i += 4) {
            int idx = i + g;
            if (idx < end) {
                int s = colsrc[idx];
                float av = __expf(lrelu(es2[s] + edv)) * rs;
                f32x2 a = (f32x2){av, av};
                unsigned w = *(const unsigned*)(h2f + (size_t)s * HID + q * 4);
                f32x2 p;
                p = __builtin_amdgcn_cvt_pk_f32_fp8(w, false); acc2[0] += p * a;
                p = __builtin_amdgcn_cvt_pk_f32_fp8(w, true);  acc2[1] += p * a;
            }
        }
    }

    float acc[4] = {acc2[0][0], acc2[0][1], acc2[1][0], acc2[1][1]};
    #pragma unroll
    for (int j = 0; j < 4; ++j) {
        acc[j] += __shfl_xor(acc[j], 16);
        acc[j] += __shfl_xor(acc[j], 32);
    }

    float v0 = __shfl(acc[0], lane >> 2);
    float v1 = __shfl(acc[1], lane >> 2);
    float v2 = __shfl(acc[2], lane >> 2);
    float v3 = __shfl(acc[3], lane >> 2);
    int jj = lane & 3;
    float o = jj == 0 ? v0 : jj == 1 ? v1 : jj == 2 ? v2 : v3;
    h3[(size_t)n * HID + lane] = f2bf(eluf(o + b2[lane]));
}

// ---------------- fused mean-pool + classifier (bf16 h3) ----------------
__global__ __launch_bounds__(256) void k_poolcls(const unsigned short* __restrict__ h3,
                                                 const int* __restrict__ gstart,
                                                 const float* __restrict__ Wc,
                                                 const float* __restrict__ bc,
                                                 float* __restrict__ out) {
    __shared__ float red[4][64];
    int g = blockIdx.x;
    int lane = threadIdx.x & 63, wv = threadIdx.x >> 6;
    int gs = gstart[g], ge = gstart[g + 1];
    float acc = 0.f;
    for (int r = gs + wv; r < ge; r += 4)
        acc += bf2f(h3[(size_t)r * HID + lane]);
    red[wv][lane] = acc;
    __syncthreads();
    if (wv == 0) {
        float p = red[0][lane] + red[1][lane] + red[2][lane] + red[3][lane];
        float c = fmaxf((float)(ge - gs), 1.f);
        p /= c;
        float s0 = p * Wc[lane * 2 + 0];
        float s1 = p * Wc[lane * 2 + 1];
        #pragma unroll
        for (int off = 1; off < 64; off <<= 1) {
            s0 += __shfl_xor(s0, off);
            s1 += __shfl_xor(s1, off);
        }
        if (lane == 0) {
            out[g * 2 + 0] = s0 + bc[0];
            out[g * 2 + 1] = s1 + bc[1];
        }
    }
}

extern "C" void kernel_launch(void* const* d_in, const int* in_sizes, int n_in,
                              void* d_out, int out_size, void* d_ws, size_t ws_size,
                              hipStream_t stream) {
    const float* x   = (const float*)d_in[0];
    const int* ei    = (const int*)d_in[1];
    const int* batch = (const int*)d_in[2];
    const float* W1  = (const float*)d_in[4];
    const float* as1 = (const float*)d_in[5];
    const float* ad1 = (const float*)d_in[6];
    const float* b1  = (const float*)d_in[7];
    const float* W2  = (const float*)d_in[8];
    const float* as2 = (const float*)d_in[9];
    const float* ad2 = (const float*)d_in[10];
    const float* b2  = (const float*)d_in[11];
    const float* Wc  = (const float*)d_in[12];
    const float* bc  = (const float*)d_in[13];
    float* out = (float*)d_out;

    char* p = (char*)d_ws;
    auto alloc = [&](size_t bytes) -> char* {
        char* r = p;
        p += (bytes + 255) & ~(size_t)255;
        return r;
    };
    int* offs    = (int*)alloc((NN + 1) * sizeof(int));
    int* colsrc  = (int*)alloc((size_t)ETOT * sizeof(int));
    int* ebuf    = (int*)alloc((size_t)NE * sizeof(int));   // packed dlocal<<17|src
    int* bhistp  = (int*)alloc(NHIST * NBUK * sizeof(int)); // partial histograms
    int* bcur    = (int*)alloc(NBUK * sizeof(int));
    int* gstart  = (int*)alloc((NG + 1) * sizeof(int));
    unsigned short* W1t = (unsigned short*)alloc((size_t)FIN * C1 * sizeof(short));
    unsigned short* W2t = (unsigned short*)alloc((size_t)C1 * HID * sizeof(short));
    unsigned char* h1f  = (unsigned char*)alloc((size_t)NN * C1);          // fp8 h1
    unsigned short* h1p = (unsigned short*)alloc((size_t)NN * C1 * sizeof(short));
    unsigned char* h2f  = (unsigned char*)alloc((size_t)NN * HID);         // fp8 h2
    float* es1   = (float*)alloc((size_t)NN * 4 * sizeof(float));
    float* ed1   = (float*)alloc((size_t)NN * 4 * sizeof(float));
    float* es2v  = (float*)alloc((size_t)NN * sizeof(float));
    float* ed2v  = (float*)alloc((size_t)NN * sizeof(float));
    unsigned short* h3 = (unsigned short*)alloc((size_t)NN * HID * sizeof(short));  // bf16

    const int* srcA = ei;       // edge_index[0]
    const int* dstA = ei + NE;  // edge_index[1]

    k_setup<<<NPREP + NHIST + 1, 256, 0, stream>>>(W1, W2, dstA, batch, W1t, W2t,
                                                   bhistp, bcur, offs, gstart);
    k_part_gemm1<<<NCHUNK + 2 * NGEMM1, 256, 0, stream>>>(srcA, dstA, bhistp, bcur, ebuf,
                                                          x, W1t, as1, ad1, h1f, es1, ed1);
    k_bfill<<<NBUK, 1024, 0, stream>>>(ebuf, bhistp, offs, colsrc);

    k_agg1<<<(NN + 7) / 8, 512, 0, stream>>>(offs, colsrc, h1f, es1, ed1, b1, h1p);
    k_gemm2<<<(NN / 16 + 3) / 4, 256, 0, stream>>>(h1p, W2t, as2, ad2, h2f, es2v, ed2v);
    k_agg2<<<(NN + 7) / 8, 512, 0, stream>>>(offs, colsrc, h2f, es2v, ed2v, b2, h3);
    k_poolcls<<<NG, 256, 0, stream>>>(h3, gstart, Wc, bc, out);
}

// Round 15
// 163.214 us; speedup vs baseline: 1.0405x; 1.0405x over previous
//
#include <hip/hip_runtime.h>

#define NN   50000
#define NE   1000000
#define FIN  128
#define HID  64
#define HEADS 4
#define C1   256          // HEADS*HID
#define NG   512
#define ETOT (NE + NN)    // edges + self-loops
#define BSH  10           // bucket = dst >> 10 (1024 nodes/bucket)
#define NBUK 49           // ceil(NN/1024)
#define CHUNK 2048
#define NCHUNK 489        // ceil(NE/CHUNK)
#define NPREP 192         // (FIN*C1 + C1*HID)/256
#define NHIST 64
#define NGEMM1 782        // row-tile groups (x2 ch blocks)

typedef __attribute__((ext_vector_type(8))) short bf16x8;
typedef __attribute__((ext_vector_type(4))) float f32x4;
typedef __attribute__((ext_vector_type(2))) float f32x2;

__device__ __forceinline__ float lrelu(float v) { return v > 0.f ? v : 0.2f * v; }
__device__ __forceinline__ float eluf(float v)  { return v > 0.f ? v : __expf(v) - 1.f; }

__device__ __forceinline__ unsigned short f2bf(float f) {
    unsigned u = __float_as_uint(f);
    unsigned r = (u + 0x7FFFu + ((u >> 16) & 1u)) >> 16;
    return (unsigned short)r;
}
__device__ __forceinline__ float bf2f(unsigned short b) {
    return __uint_as_float(((unsigned)b) << 16);
}
__device__ __forceinline__ unsigned char f2fp8(float f) {
    int w = __builtin_amdgcn_cvt_pk_fp8_f32(f, f, 0, false);
    return (unsigned char)(w & 0xFF);
}

// ---------------- fused setup: weight prep + partial hist + gstart + bcur zero ----------------
// bhistp layout: [NBUK][NHIST] (transposed for coalesced per-lane summation)
__global__ __launch_bounds__(256) void k_setup(const float* __restrict__ W1,
                                               const float* __restrict__ W2,
                                               const int* __restrict__ dst,
                                               const int* __restrict__ batch,
                                               unsigned short* __restrict__ W1t,
                                               unsigned short* __restrict__ W2t,
                                               int* __restrict__ bhistp,
                                               int* __restrict__ bcur,
                                               int* __restrict__ offs,
                                               int* __restrict__ gstart) {
    int b = blockIdx.x;
    int tid = threadIdx.x;
    if (b < NPREP) {
        int i = b * 256 + tid;
        if (i < FIN * C1) {
            int k = i / C1, c = i % C1;
            W1t[c * FIN + k] = f2bf(W1[i]);
        } else {
            int j = i - FIN * C1;
            if (j < C1 * HID) {
                int k = j / HID, c = j % HID;
                W2t[c * C1 + k] = f2bf(W2[j]);
            }
        }
    } else if (b < NPREP + NHIST) {
        __shared__ int lh[NBUK];
        if (tid < NBUK) lh[tid] = 0;
        __syncthreads();
        for (int e = (b - NPREP) * 256 + tid; e < NE; e += NHIST * 256)
            atomicAdd(&lh[dst[e] >> BSH], 1);
        __syncthreads();
        if (tid < NBUK) bhistp[tid * NHIST + (b - NPREP)] = lh[tid];
    } else {
        if (tid < NBUK) bcur[tid] = 0;
        if (tid == 64) offs[NN] = ETOT;
        for (int g = tid; g <= NG; g += 256) {
            int lo = 0, hi = NN;
            while (lo < hi) {
                int mid = (lo + hi) >> 1;
                if (batch[mid] < g) lo = mid + 1; else hi = mid;
            }
            gstart[g] = lo;
        }
    }
}

// ---------------- FUSED: edge partition (blocks 0..NCHUNK) + gemm1 ch-split (rest) ----------------
__global__ __launch_bounds__(256) void k_part_gemm1(const int* __restrict__ srcA,
                                                    const int* __restrict__ dstA,
                                                    const int* __restrict__ bhistp,
                                                    int* __restrict__ bcur,
                                                    int* __restrict__ ebuf,
                                                    const float* __restrict__ x,
                                                    const unsigned short* __restrict__ W1t,
                                                    const float* __restrict__ asrc,
                                                    const float* __restrict__ adst,
                                                    unsigned char* __restrict__ h1f,
                                                    float* __restrict__ es1,
                                                    float* __restrict__ ed1) {
    __shared__ int lsh[128 * FIN / 2];   // 32 KB, reused by both roles
    int tid = threadIdx.x;

    if (blockIdx.x < NCHUNK) {
        // ---- partition role ----
        int* lcnt  = lsh;
        int* gbase = lsh + NBUK;
        int* lrank = lsh + 2 * NBUK;
        int* sbase = lsh + 3 * NBUK;
        if (tid < NBUK) {
            const int* hp = bhistp + tid * NHIST;
            int s = 0;
            #pragma unroll 16
            for (int j = 0; j < NHIST; ++j) s += hp[j];   // coalesced per-lane stream
            lcnt[tid] = 0; lrank[tid] = 0;
            lsh[4 * NBUK + tid] = s;                      // stash ssum
        }
        __syncthreads();
        if (tid < 64) {
            int v = (tid < NBUK) ? lsh[4 * NBUK + tid] : 0;
            int xs = v;
            #pragma unroll
            for (int off = 1; off < 64; off <<= 1) {
                int t = __shfl_up(xs, off);
                if (tid >= off) xs += t;
            }
            if (tid < NBUK) sbase[tid] = xs - v;   // exclusive
        }
        __syncthreads();
        int e0 = blockIdx.x * CHUNK;
        int e1 = min(e0 + CHUNK, NE);
        for (int e = e0 + tid; e < e1; e += 256)
            atomicAdd(&lcnt[dstA[e] >> BSH], 1);
        __syncthreads();
        if (tid < NBUK) gbase[tid] = sbase[tid] + atomicAdd(&bcur[tid], lcnt[tid]);
        __syncthreads();
        for (int e = e0 + tid; e < e1; e += 256) {
            int d = dstA[e];
            int b = d >> BSH;
            int r = atomicAdd(&lrank[b], 1);
            ebuf[gbase[b] + r] = ((d & 1023) << 17) | srcA[e];
        }
        return;
    }

    // ---- gemm1 role: one block = one (row-tile-group, ch) pair ----
    unsigned short* Wl = (unsigned short*)lsh;
    int g1 = blockIdx.x - NCHUNK;
    int rt = g1 >> 1;
    int ch = g1 & 1;          // column half: cols [ch*128, ch*128+128)
    int lane = tid & 63, wv = tid >> 6;
    int r0 = (rt * 4 + wv) * 16;
    int g = lane >> 4, q = lane & 15;

    int ar = min(r0 + q, NN - 1);
    const float* xr = x + (size_t)ar * FIN;
    bf16x8 afr[4];
    #pragma unroll
    for (int kt = 0; kt < 4; ++kt) {
        float4 u0 = *(const float4*)(xr + kt * 32 + g * 8);
        float4 u1 = *(const float4*)(xr + kt * 32 + g * 8 + 4);
        bf16x8 a;
        a[0] = (short)f2bf(u0.x); a[1] = (short)f2bf(u0.y);
        a[2] = (short)f2bf(u0.z); a[3] = (short)f2bf(u0.w);
        a[4] = (short)f2bf(u1.x); a[5] = (short)f2bf(u1.y);
        a[6] = (short)f2bf(u1.z); a[7] = (short)f2bf(u1.w);
        afr[kt] = a;
    }

    const uint4* src = (const uint4*)(W1t + (size_t)ch * 128 * FIN);
    #pragma unroll
    for (int i = 0; i < 8; ++i) {
        int idx = tid + i * 256;
        uint4 v = src[idx];
        unsigned byte = (unsigned)idx << 4;
        unsigned dst = byte ^ (((byte >> 8) & 7) << 4);
        *(uint4*)((char*)Wl + dst) = v;
    }
    __syncthreads();

    #pragma unroll
    for (int hh = 0; hh < 2; ++hh) {
        int h = ch * 2 + hh;
        float ps[4] = {0.f, 0.f, 0.f, 0.f};
        float pd[4] = {0.f, 0.f, 0.f, 0.f};
        #pragma unroll
        for (int tl = 0; tl < 4; ++tl) {
            int col = (h * 4 + tl) * 16 + q;
            int cl = col - ch * 128;
            f32x4 acc = {0.f, 0.f, 0.f, 0.f};
            #pragma unroll
            for (int kt = 0; kt < 4; ++kt) {
                unsigned bb = (unsigned)cl * 256 + kt * 64 + g * 16;
                bf16x8 b = *(const bf16x8*)((const char*)Wl + (bb ^ (((unsigned)cl & 7) << 4)));
                acc = __builtin_amdgcn_mfma_f32_16x16x32_bf16(afr[kt], b, acc, 0, 0, 0);
            }
            float av = asrc[col], bv = adst[col];
            #pragma unroll
            for (int j = 0; j < 4; ++j) {
                int rr = min(r0 + g * 4 + j, NN - 1);
                h1f[(size_t)rr * C1 + col] = f2fp8(acc[j]);
                ps[j] += acc[j] * av;
                pd[j] += acc[j] * bv;
            }
        }
        #pragma unroll
        for (int j = 0; j < 4; ++j) {
            #pragma unroll
            for (int off = 1; off < 16; off <<= 1) {
                ps[j] += __shfl_xor(ps[j], off);
                pd[j] += __shfl_xor(pd[j], off);
            }
            if (q == 0) {
                int rr = min(r0 + g * 4 + j, NN - 1);
                es1[rr * 4 + h] = ps[j];
                ed1[rr * 4 + h] = pd[j];
            }
        }
    }
}

// per-bucket: local degrees -> scan -> offs + colsrc fill (all XCD-local)
__global__ __launch_bounds__(1024) void k_bfill(const int* __restrict__ ebuf,
                                                const int* __restrict__ bhistp,
                                                int* __restrict__ offs,
                                                int* __restrict__ colsrc) {
    __shared__ int ldeg[1024];
    __shared__ int lcur[1024];
    __shared__ int ws[16];
    __shared__ int ssum[NBUK];
    __shared__ int sbase[NBUK];
    int b = blockIdx.x;
    int tid = threadIdx.x;
    int nbase = b << BSH;
    int ncnt = min(1024, NN - nbase);
    if (tid < NBUK) {
        const int* hp = bhistp + tid * NHIST;
        int s = 0;
        #pragma unroll 16
        for (int j = 0; j < NHIST; ++j) s += hp[j];
        ssum[tid] = s;
    }
    ldeg[tid] = 0;
    __syncthreads();
    if (tid < 64) {
        int v = (tid < NBUK) ? ssum[tid] : 0;
        int xs = v;
        #pragma unroll
        for (int off = 1; off < 64; off <<= 1) {
            int t = __shfl_up(xs, off);
            if (tid >= off) xs += t;
        }
        if (tid < NBUK) sbase[tid] = xs - v;   // exclusive
    }
    __syncthreads();
    int ebeg = sbase[b], eend = sbase[b] + ssum[b];
    for (int i = ebeg + tid; i < eend; i += 1024)
        atomicAdd(&ldeg[ebuf[i] >> 17], 1);
    __syncthreads();
    int v = (tid < ncnt) ? ldeg[tid] + 1 : 0;
    int lane = tid & 63, wv = tid >> 6;
    int x = v;
    #pragma unroll
    for (int off = 1; off < 64; off <<= 1) {
        int t = __shfl_up(x, off);
        if (lane >= off) x += t;
    }
    if (lane == 63) ws[wv] = x;
    __syncthreads();
    if (tid < 16) {
        int y = ws[tid];
        #pragma unroll
        for (int off = 1; off < 16; off <<= 1) {
            int t = __shfl_up(y, off);
            if (tid >= off) y += t;
        }
        ws[tid] = y;
    }
    __syncthreads();
    int base = wv ? ws[wv - 1] : 0;
    int excl = base + x - v;
    int gofs = ebeg + nbase + excl;
    if (tid < ncnt) {
        offs[nbase + tid] = gofs;
        lcur[tid] = gofs;
    }
    __syncthreads();
    for (int i = ebeg + tid; i < eend; i += 1024) {
        int pe = ebuf[i];
        int p = atomicAdd(&lcur[pe >> 17], 1);
        colsrc[p] = pe & 0x1FFFF;
    }
    __syncthreads();
    if (tid < ncnt) colsrc[lcur[tid]] = nbase + tid;   // self-loop at segment end
}

// ---------------- Layer 1 aggregation: fp8 gathers, 4-load interleave ----------------
__global__ __launch_bounds__(512) void k_agg1(const int* __restrict__ offs,
                                              const int* __restrict__ colsrc,
                                              const unsigned char* __restrict__ h1f,
                                              const float* __restrict__ es1,
                                              const float* __restrict__ ed1,
                                              const float* __restrict__ b1,
                                              unsigned short* __restrict__ h1p) {
    __shared__ int   sls[8][64];
    __shared__ float sla[8][64][4];
    int lane = threadIdx.x & 63, wv = threadIdx.x >> 6;
    int n = blockIdx.x * 8 + wv;
    if (n >= NN) return;
    int beg = offs[n], end = offs[n + 1], deg = end - beg;
    float4 edv = *(const float4*)(ed1 + n * 4);
    int half = lane >> 5, q5 = lane & 31;
    int hd = q5 >> 3;
    f32x2 acc2[4];
    #pragma unroll
    for (int j = 0; j < 4; ++j) acc2[j] = (f32x2){0.f, 0.f};

    if (deg <= 64) {
        int msrc = 0;
        float m0 = 0.f, m1 = 0.f, m2 = 0.f, m3 = 0.f;
        if (lane < deg) {
            msrc = colsrc[beg + lane];
            float4 ev = *(const float4*)(es1 + msrc * 4);
            m0 = __expf(lrelu(ev.x + edv.x));
            m1 = __expf(lrelu(ev.y + edv.y));
            m2 = __expf(lrelu(ev.z + edv.z));
            m3 = __expf(lrelu(ev.w + edv.w));
        }
        float s0 = m0, s1 = m1, s2 = m2, s3 = m3;
        #pragma unroll
        for (int off = 1; off < 64; off <<= 1) {
            s0 += __shfl_xor(s0, off);
            s1 += __shfl_xor(s1, off);
            s2 += __shfl_xor(s2, off);
            s3 += __shfl_xor(s3, off);
        }
        sls[wv][lane] = msrc;
        sla[wv][lane][0] = m0 * (1.f / s0);
        sla[wv][lane][1] = m1 * (1.f / s1);
        sla[wv][lane][2] = m2 * (1.f / s2);
        sla[wv][lane][3] = m3 * (1.f / s3);

        for (int i = 0; i < deg; i += 8) {
            int e0 = (i + half) & 63, e1 = (i + 2 + half) & 63, e2 = (i + 4 + half) & 63, e3 = (i + 6 + half) & 63;
            int   s0i = sls[wv][e0], s1i = sls[wv][e1], s2i = sls[wv][e2], s3i = sls[wv][e3];
            f32x2 a0 = (f32x2){sla[wv][e0][hd], sla[wv][e0][hd]};
            f32x2 a1 = (f32x2){sla[wv][e1][hd], sla[wv][e1][hd]};
            f32x2 a2 = (f32x2){sla[wv][e2][hd], sla[wv][e2][hd]};
            f32x2 a3 = (f32x2){sla[wv][e3][hd], sla[wv][e3][hd]};
            uint2 h0 = *(const uint2*)(h1f + (size_t)s0i * C1 + q5 * 8);
            uint2 h1 = *(const uint2*)(h1f + (size_t)s1i * C1 + q5 * 8);
            uint2 h2 = *(const uint2*)(h1f + (size_t)s2i * C1 + q5 * 8);
            uint2 h3 = *(const uint2*)(h1f + (size_t)s3i * C1 + q5 * 8);
            f32x2 p;
            p = __builtin_amdgcn_cvt_pk_f32_fp8(h0.x, false); acc2[0] += p * a0;
            p = __builtin_amdgcn_cvt_pk_f32_fp8(h0.x, true);  acc2[1] += p * a0;
            p = __builtin_amdgcn_cvt_pk_f32_fp8(h0.y, false); acc2[2] += p * a0;
            p = __builtin_amdgcn_cvt_pk_f32_fp8(h0.y, true);  acc2[3] += p * a0;
            p = __builtin_amdgcn_cvt_pk_f32_fp8(h1.x, false); acc2[0] += p * a1;
            p = __builtin_amdgcn_cvt_pk_f32_fp8(h1.x, true);  acc2[1] += p * a1;
            p = __builtin_amdgcn_cvt_pk_f32_fp8(h1.y, false); acc2[2] += p * a1;
            p = __builtin_amdgcn_cvt_pk_f32_fp8(h1.y, true);  acc2[3] += p * a1;
            p = __builtin_amdgcn_cvt_pk_f32_fp8(h2.x, false); acc2[0] += p * a2;
            p = __builtin_amdgcn_cvt_pk_f32_fp8(h2.x, true);  acc2[1] += p * a2;
            p = __builtin_amdgcn_cvt_pk_f32_fp8(h2.y, false); acc2[2] += p * a2;
            p = __builtin_amdgcn_cvt_pk_f32_fp8(h2.y, true);  acc2[3] += p * a2;
            p = __builtin_amdgcn_cvt_pk_f32_fp8(h3.x, false); acc2[0] += p * a3;
            p = __builtin_amdgcn_cvt_pk_f32_fp8(h3.x, true);  acc2[1] += p * a3;
            p = __builtin_amdgcn_cvt_pk_f32_fp8(h3.y, false); acc2[2] += p * a3;
            p = __builtin_amdgcn_cvt_pk_f32_fp8(h3.y, true);  acc2[3] += p * a3;
        }
    } else {
        float s0 = 0.f, s1 = 0.f, s2 = 0.f, s3 = 0.f;
        for (int i = beg + lane; i < end; i += 64) {
            int s = colsrc[i];
            float4 ev = *(const float4*)(es1 + s * 4);
            s0 += __expf(lrelu(ev.x + edv.x));
            s1 += __expf(lrelu(ev.y + edv.y));
            s2 += __expf(lrelu(ev.z + edv.z));
            s3 += __expf(lrelu(ev.w + edv.w));
        }
        #pragma unroll
        for (int off = 1; off < 64; off <<= 1) {
            s0 += __shfl_xor(s0, off);
            s1 += __shfl_xor(s1, off);
            s2 += __shfl_xor(s2, off);
            s3 += __shfl_xor(s3, off);
        }
        float rr = hd == 0 ? 1.f / s0 : hd == 1 ? 1.f / s1 : hd == 2 ? 1.f / s2 : 1.f / s3;
        float ed_h = hd == 0 ? edv.x : hd == 1 ? edv.y : hd == 2 ? edv.z : edv.w;
        for (int i = beg; i < end; i += 2) {
            int idx = i + half;
            if (idx < end) {
                int s = colsrc[idx];
                float eh = es1[s * 4 + hd] + ed_h;
                float av = __expf(lrelu(eh)) * rr;
                f32x2 a = (f32x2){av, av};
                uint2 hv = *(const uint2*)(h1f + (size_t)s * C1 + q5 * 8);
                f32x2 p;
                p = __builtin_amdgcn_cvt_pk_f32_fp8(hv.x, false); acc2[0] += p * a;
                p = __builtin_amdgcn_cvt_pk_f32_fp8(hv.x, true);  acc2[1] += p * a;
                p = __builtin_amdgcn_cvt_pk_f32_fp8(hv.y, false); acc2[2] += p * a;
                p = __builtin_amdgcn_cvt_pk_f32_fp8(hv.y, true);  acc2[3] += p * a;
            }
        }
    }

    float acc[8];
    #pragma unroll
    for (int j = 0; j < 4; ++j) { acc[2*j] = acc2[j][0]; acc[2*j+1] = acc2[j][1]; }
    #pragma unroll
    for (int j = 0; j < 8; ++j) acc[j] += __shfl_xor(acc[j], 32);

    if (half == 0) {
        float4 bv0 = *(const float4*)(b1 + q5 * 8);
        float4 bv1 = *(const float4*)(b1 + q5 * 8 + 4);
        bf16x8 o;
        o[0] = (short)f2bf(eluf(acc[0] + bv0.x));
        o[1] = (short)f2bf(eluf(acc[1] + bv0.y));
        o[2] = (short)f2bf(eluf(acc[2] + bv0.z));
        o[3] = (short)f2bf(eluf(acc[3] + bv0.w));
        o[4] = (short)f2bf(eluf(acc[4] + bv1.x));
        o[5] = (short)f2bf(eluf(acc[5] + bv1.y));
        o[6] = (short)f2bf(eluf(acc[6] + bv1.z));
        o[7] = (short)f2bf(eluf(acc[7] + bv1.w));
        *(bf16x8*)(h1p + (size_t)n * C1 + q5 * 8) = o;
    }
}

// ---------------- Layer 2 GEMM (MFMA bf16, LDS-staged W, fp8 h2 output) ----------------
__global__ __launch_bounds__(256) void k_gemm2(const unsigned short* __restrict__ h1p,
                                               const unsigned short* __restrict__ W2t,
                                               const float* __restrict__ as2,
                                               const float* __restrict__ ad2,
                                               unsigned char* __restrict__ h2f,
                                               float* __restrict__ es2,
                                               float* __restrict__ ed2) {
    __shared__ unsigned short Wl[HID * C1];   // 32 KB
    int tid = threadIdx.x;
    int lane = tid & 63, wv = tid >> 6;
    int r0 = (blockIdx.x * 4 + wv) * 16;
    int g = lane >> 4, q = lane & 15;

    const uint4* src = (const uint4*)W2t;
    #pragma unroll
    for (int i = 0; i < 8; ++i) {
        int idx = tid + i * 256;
        uint4 v = src[idx];
        unsigned byte = (unsigned)idx << 4;
        unsigned dst = byte ^ (((byte >> 9) & 7) << 4);
        *(uint4*)((char*)Wl + dst) = v;
    }

    int ar = min(r0 + q, NN - 1);
    const unsigned short* arp = h1p + (size_t)ar * C1;
    bf16x8 afr[8];
    #pragma unroll
    for (int kt = 0; kt < 8; ++kt)
        afr[kt] = *(const bf16x8*)(arp + kt * 32 + g * 8);

    __syncthreads();

    float ps[4] = {0.f, 0.f, 0.f, 0.f};
    float pd[4] = {0.f, 0.f, 0.f, 0.f};
    #pragma unroll
    for (int t = 0; t < 4; ++t) {
        int col = t * 16 + q;
        f32x4 acc = {0.f, 0.f, 0.f, 0.f};
        #pragma unroll
        for (int kt = 0; kt < 8; ++kt) {
            unsigned bb = (unsigned)col * 512 + kt * 64 + g * 16;
            bf16x8 b = *(const bf16x8*)((const char*)Wl + (bb ^ (((unsigned)col & 7) << 4)));
            acc = __builtin_amdgcn_mfma_f32_16x16x32_bf16(afr[kt], b, acc, 0, 0, 0);
        }
        float av = as2[col], bv = ad2[col];
        #pragma unroll
        for (int j = 0; j < 4; ++j) {
            int rr = min(r0 + g * 4 + j, NN - 1);
            h2f[(size_t)rr * HID + col] = f2fp8(acc[j]);
            ps[j] += acc[j] * av;
            pd[j] += acc[j] * bv;
        }
    }
    #pragma unroll
    for (int j = 0; j < 4; ++j) {
        #pragma unroll
        for (int off = 1; off < 16; off <<= 1) {
            ps[j] += __shfl_xor(ps[j], off);
            pd[j] += __shfl_xor(pd[j], off);
        }
        if (q == 0) {
            int rr = min(r0 + g * 4 + j, NN - 1);
            es2[rr] = ps[j];
            ed2[rr] = pd[j];
        }
    }
}

// ---------------- Layer 2 aggregation: fp8 gathers, 4-load interleave, bf16 h3 ----------------
__global__ __launch_bounds__(512) void k_agg2(const int* __restrict__ offs,
                                              const int* __restrict__ colsrc,
                                              const unsigned char* __restrict__ h2f,
                                              const float* __restrict__ es2,
                                              const float* __restrict__ ed2,
                                              const float* __restrict__ b2,
                                              unsigned short* __restrict__ h3) {
    __shared__ int   sls[8][64];
    __shared__ float sla[8][64];
    int lane = threadIdx.x & 63, wv = threadIdx.x >> 6;
    int n = blockIdx.x * 8 + wv;
    if (n >= NN) return;
    int beg = offs[n], end = offs[n + 1], deg = end - beg;
    float edv = ed2[n];
    int g = lane >> 4, q = lane & 15;
    f32x2 acc2[2];
    acc2[0] = (f32x2){0.f, 0.f};
    acc2[1] = (f32x2){0.f, 0.f};

    if (deg <= 64) {
        int msrc = 0;
        float mex = 0.f;
        if (lane < deg) {
            msrc = colsrc[beg + lane];
            mex = __expf(lrelu(es2[msrc] + edv));
        }
        float ss = mex;
        #pragma unroll
        for (int off = 1; off < 64; off <<= 1) ss += __shfl_xor(ss, off);
        sls[wv][lane] = msrc;
        sla[wv][lane] = mex * (1.f / ss);

        for (int i = 0; i < deg; i += 16) {
            int e0 = (i + g) & 63, e1 = (i + 4 + g) & 63, e2 = (i + 8 + g) & 63, e3 = (i + 12 + g) & 63;
            int   s0i = sls[wv][e0], s1i = sls[wv][e1], s2i = sls[wv][e2], s3i = sls[wv][e3];
            f32x2 a0 = (f32x2){sla[wv][e0], sla[wv][e0]};
            f32x2 a1 = (f32x2){sla[wv][e1], sla[wv][e1]};
            f32x2 a2 = (f32x2){sla[wv][e2], sla[wv][e2]};
            f32x2 a3 = (f32x2){sla[wv][e3], sla[wv][e3]};
            unsigned w0 = *(const unsigned*)(h2f + (size_t)s0i * HID + q * 4);
            unsigned w1 = *(const unsigned*)(h2f + (size_t)s1i * HID + q * 4);
            unsigned w2 = *(const unsigned*)(h2f + (size_t)s2i * HID + q * 4);
            unsigned w3 = *(const unsigned*)(h2f + (size_t)s3i * HID + q * 4);
            f32x2 p;
            p = __builtin_amdgcn_cvt_pk_f32_fp8(w0, false); acc2[0] += p * a0;
            p = __builtin_amdgcn_cvt_pk_f32_fp8(w0, true);  acc2[1] += p * a0;
            p = __builtin_amdgcn_cvt_pk_f32_fp8(w1, false); acc2[0] += p * a1;
            p = __builtin_amdgcn_cvt_pk_f32_fp8(w1, true);  acc2[1] += p * a1;
            p = __builtin_amdgcn_cvt_pk_f32_fp8(w2, false); acc2[0] += p * a2;
            p = __builtin_amdgcn_cvt_pk_f32_fp8(w2, true);  acc2[1] += p * a2;
            p = __builtin_amdgcn_cvt_pk_f32_fp8(w3, false); acc2[0] += p * a3;
            p = __builtin_amdgcn_cvt_pk_f32_fp8(w3, true);  acc2[1] += p * a3;
        }
    } else {
        float ss = 0.f;
        for (int i = beg + lane; i < end; i += 64) {
            int s = colsrc[i];
            ss += __expf(lrelu(es2[s] + edv));
        }
        #pragma unroll
        for (int off = 1; off < 64; off <<= 1) ss += __shfl_xor(ss, off);
        float rs = 1.f / ss;
        for (int i = beg; i < end; i += 4) {
            int idx = i + g;
            if (idx < end) {
                int s = colsrc[idx];
                float av = __expf(lrelu(es2[s] + edv)) * rs;
                f32x2 a = (f32x2){av, av};
                unsigned w = *(const unsigned*)(h2f + (size_t)s * HID + q * 4);
                f32x2 p;
                p = __builtin_amdgcn_cvt_pk_f32_fp8(w, false); acc2[0] += p * a;
                p = __builtin_amdgcn_cvt_pk_f32_fp8(w, true);  acc2[1] += p * a;
            }
        }
    }

    float acc[4] = {acc2[0][0], acc2[0][1], acc2[1][0], acc2[1][1]};
    #pragma unroll
    for (int j = 0; j < 4; ++j) {
        acc[j] += __shfl_xor(acc[j], 16);
        acc[j] += __shfl_xor(acc[j], 32);
    }

    float v0 = __shfl(acc[0], lane >> 2);
    float v1 = __shfl(acc[1], lane >> 2);
    float v2 = __shfl(acc[2], lane >> 2);
    float v3 = __shfl(acc[3], lane >> 2);
    int jj = lane & 3;
    float o = jj == 0 ? v0 : jj == 1 ? v1 : jj == 2 ? v2 : v3;
    h3[(size_t)n * HID + lane] = f2bf(eluf(o + b2[lane]));
}

// ---------------- fused mean-pool + classifier (bf16 h3) ----------------
__global__ __launch_bounds__(256) void k_poolcls(const unsigned short* __restrict__ h3,
                                                 const int* __restrict__ gstart,
                                                 const float* __restrict__ Wc,
                                                 const float* __restrict__ bc,
                                                 float* __restrict__ out) {
    __shared__ float red[4][64];
    int g = blockIdx.x;
    int lane = threadIdx.x & 63, wv = threadIdx.x >> 6;
    int gs = gstart[g], ge = gstart[g + 1];
    float acc = 0.f;
    for (int r = gs + wv; r < ge; r += 4)
        acc += bf2f(h3[(size_t)r * HID + lane]);
    red[wv][lane] = acc;
    __syncthreads();
    if (wv == 0) {
        float p = red[0][lane] + red[1][lane] + red[2][lane] + red[3][lane];
        float c = fmaxf((float)(ge - gs), 1.f);
        p /= c;
        float s0 = p * Wc[lane * 2 + 0];
        float s1 = p * Wc[lane * 2 + 1];
        #pragma unroll
        for (int off = 1; off < 64; off <<= 1) {
            s0 += __shfl_xor(s0, off);
            s1 += __shfl_xor(s1, off);
        }
        if (lane == 0) {
            out[g * 2 + 0] = s0 + bc[0];
            out[g * 2 + 1] = s1 + bc[1];
        }
    }
}

extern "C" void kernel_launch(void* const* d_in, const int* in_sizes, int n_in,
                              void* d_out, int out_size, void* d_ws, size_t ws_size,
                              hipStream_t stream) {
    const float* x   = (const float*)d_in[0];
    const int* ei    = (const int*)d_in[1];
    const int* batch = (const int*)d_in[2];
    const float* W1  = (const float*)d_in[4];
    const float* as1 = (const float*)d_in[5];
    const float* ad1 = (const float*)d_in[6];
    const float* b1  = (const float*)d_in[7];
    const float* W2  = (const float*)d_in[8];
    const float* as2 = (const float*)d_in[9];
    const float* ad2 = (const float*)d_in[10];
    const float* b2  = (const float*)d_in[11];
    const float* Wc  = (const float*)d_in[12];
    const float* bc  = (const float*)d_in[13];
    float* out = (float*)d_out;

    char* p = (char*)d_ws;
    auto alloc = [&](size_t bytes) -> char* {
        char* r = p;
        p += (bytes + 255) & ~(size_t)255;
        return r;
    };
    int* offs    = (int*)alloc((NN + 1) * sizeof(int));
    int* colsrc  = (int*)alloc((size_t)ETOT * sizeof(int));
    int* ebuf    = (int*)alloc((size_t)NE * sizeof(int));   // packed dlocal<<17|src
    int* bhistp  = (int*)alloc(NBUK * NHIST * sizeof(int)); // partial histograms [NBUK][NHIST]
    int* bcur    = (int*)alloc(NBUK * sizeof(int));
    int* gstart  = (int*)alloc((NG + 1) * sizeof(int));
    unsigned short* W1t = (unsigned short*)alloc((size_t)FIN * C1 * sizeof(short));
    unsigned short* W2t = (unsigned short*)alloc((size_t)C1 * HID * sizeof(short));
    unsigned char* h1f  = (unsigned char*)alloc((size_t)NN * C1);          // fp8 h1
    unsigned short* h1p = (unsigned short*)alloc((size_t)NN * C1 * sizeof(short));
    unsigned char* h2f  = (unsigned char*)alloc((size_t)NN * HID);         // fp8 h2
    float* es1   = (float*)alloc((size_t)NN * 4 * sizeof(float));
    float* ed1   = (float*)alloc((size_t)NN * 4 * sizeof(float));
    float* es2v  = (float*)alloc((size_t)NN * sizeof(float));
    float* ed2v  = (float*)alloc((size_t)NN * sizeof(float));
    unsigned short* h3 = (unsigned short*)alloc((size_t)NN * HID * sizeof(short));  // bf16

    const int* srcA = ei;       // edge_index[0]
    const int* dstA = ei + NE;  // edge_index[1]

    k_setup<<<NPREP + NHIST + 1, 256, 0, stream>>>(W1, W2, dstA, batch, W1t, W2t,
                                                   bhistp, bcur, offs, gstart);
    k_part_gemm1<<<NCHUNK + 2 * NGEMM1, 256, 0, stream>>>(srcA, dstA, bhistp, bcur, ebuf,
                                                          x, W1t, as1, ad1, h1f, es1, ed1);
    k_bfill<<<NBUK, 1024, 0, stream>>>(ebuf, bhistp, offs, colsrc);

    k_agg1<<<(NN + 7) / 8, 512, 0, stream>>>(offs, colsrc, h1f, es1, ed1, b1, h1p);
    k_gemm2<<<(NN / 16 + 3) / 4, 256, 0, stream>>>(h1p, W2t, as2, ad2, h2f, es2v, ed2v);
    k_agg2<<<(NN + 7) / 8, 512, 0, stream>>>(offs, colsrc, h2f, es2v, ed2v, b2, h3);
    k_poolcls<<<NG, 256, 0, stream>>>(h3, gstart, Wc, bc, out);
}

// Round 16
// 160.857 us; speedup vs baseline: 1.0557x; 1.0147x over previous
//
#include <hip/hip_runtime.h>

#define NN   50000
#define NE   1000000
#define FIN  128
#define HID  64
#define HEADS 4
#define C1   256          // HEADS*HID
#define NG   512
#define ETOT (NE + NN)    // edges + self-loops
#define BSH  10           // bucket = dst >> 10 (1024 nodes/bucket)
#define NBUK 49           // ceil(NN/1024)
#define CHUNK 2048
#define NCHUNK 489        // ceil(NE/CHUNK)
#define NPREP 192         // (FIN*C1 + C1*HID)/256
#define NHIST 64
#define NGEMM1 782        // row-tile groups (x2 ch blocks)

typedef __attribute__((ext_vector_type(8))) short bf16x8;
typedef __attribute__((ext_vector_type(4))) float f32x4;
typedef __attribute__((ext_vector_type(2))) float f32x2;

__device__ __forceinline__ float lrelu(float v) { return v > 0.f ? v : 0.2f * v; }
__device__ __forceinline__ float eluf(float v)  { return v > 0.f ? v : __expf(v) - 1.f; }

__device__ __forceinline__ unsigned short f2bf(float f) {
    unsigned u = __float_as_uint(f);
    unsigned r = (u + 0x7FFFu + ((u >> 16) & 1u)) >> 16;
    return (unsigned short)r;
}
__device__ __forceinline__ float bf2f(unsigned short b) {
    return __uint_as_float(((unsigned)b) << 16);
}
__device__ __forceinline__ unsigned char f2fp8(float f) {
    int w = __builtin_amdgcn_cvt_pk_fp8_f32(f, f, 0, false);
    return (unsigned char)(w & 0xFF);
}

// ---------------- fused setup: weight prep + partial hist + gstart + bcur zero ----------------
// bhistp layout: [NBUK][NHIST]; W2f is fp8
__global__ __launch_bounds__(256) void k_setup(const float* __restrict__ W1,
                                               const float* __restrict__ W2,
                                               const int* __restrict__ dst,
                                               const int* __restrict__ batch,
                                               unsigned short* __restrict__ W1t,
                                               unsigned char* __restrict__ W2f,
                                               int* __restrict__ bhistp,
                                               int* __restrict__ bcur,
                                               int* __restrict__ offs,
                                               int* __restrict__ gstart) {
    int b = blockIdx.x;
    int tid = threadIdx.x;
    if (b < NPREP) {
        int i = b * 256 + tid;
        if (i < FIN * C1) {
            int k = i / C1, c = i % C1;
            W1t[c * FIN + k] = f2bf(W1[i]);
        } else {
            int j = i - FIN * C1;
            if (j < C1 * HID) {
                int k = j / HID, c = j % HID;
                W2f[c * C1 + k] = f2fp8(W2[j]);
            }
        }
    } else if (b < NPREP + NHIST) {
        __shared__ int lh[NBUK];
        if (tid < NBUK) lh[tid] = 0;
        __syncthreads();
        for (int e = (b - NPREP) * 256 + tid; e < NE; e += NHIST * 256)
            atomicAdd(&lh[dst[e] >> BSH], 1);
        __syncthreads();
        if (tid < NBUK) bhistp[tid * NHIST + (b - NPREP)] = lh[tid];
    } else {
        if (tid < NBUK) bcur[tid] = 0;
        if (tid == 64) offs[NN] = ETOT;
        for (int g = tid; g <= NG; g += 256) {
            int lo = 0, hi = NN;
            while (lo < hi) {
                int mid = (lo + hi) >> 1;
                if (batch[mid] < g) lo = mid + 1; else hi = mid;
            }
            gstart[g] = lo;
        }
    }
}

// ---------------- FUSED: edge partition (blocks 0..NCHUNK) + gemm1 ch-split (rest) ----------------
__global__ __launch_bounds__(256) void k_part_gemm1(const int* __restrict__ srcA,
                                                    const int* __restrict__ dstA,
                                                    const int* __restrict__ bhistp,
                                                    int* __restrict__ bcur,
                                                    int* __restrict__ ebuf,
                                                    const float* __restrict__ x,
                                                    const unsigned short* __restrict__ W1t,
                                                    const float* __restrict__ asrc,
                                                    const float* __restrict__ adst,
                                                    unsigned char* __restrict__ h1f,
                                                    float* __restrict__ es1,
                                                    float* __restrict__ ed1) {
    __shared__ int lsh[128 * FIN / 2];   // 32 KB, reused by both roles
    int tid = threadIdx.x;

    if (blockIdx.x < NCHUNK) {
        // ---- partition role ----
        int* lcnt  = lsh;
        int* gbase = lsh + NBUK;
        int* lrank = lsh + 2 * NBUK;
        int* sbase = lsh + 3 * NBUK;
        if (tid < NBUK) {
            const int* hp = bhistp + tid * NHIST;
            int s = 0;
            #pragma unroll 16
            for (int j = 0; j < NHIST; ++j) s += hp[j];   // coalesced per-lane stream
            lcnt[tid] = 0; lrank[tid] = 0;
            lsh[4 * NBUK + tid] = s;
        }
        __syncthreads();
        if (tid < 64) {
            int v = (tid < NBUK) ? lsh[4 * NBUK + tid] : 0;
            int xs = v;
            #pragma unroll
            for (int off = 1; off < 64; off <<= 1) {
                int t = __shfl_up(xs, off);
                if (tid >= off) xs += t;
            }
            if (tid < NBUK) sbase[tid] = xs - v;   // exclusive
        }
        __syncthreads();
        int e0 = blockIdx.x * CHUNK;
        int e1 = min(e0 + CHUNK, NE);
        for (int e = e0 + tid; e < e1; e += 256)
            atomicAdd(&lcnt[dstA[e] >> BSH], 1);
        __syncthreads();
        if (tid < NBUK) gbase[tid] = sbase[tid] + atomicAdd(&bcur[tid], lcnt[tid]);
        __syncthreads();
        for (int e = e0 + tid; e < e1; e += 256) {
            int d = dstA[e];
            int b = d >> BSH;
            int r = atomicAdd(&lrank[b], 1);
            ebuf[gbase[b] + r] = ((d & 1023) << 17) | srcA[e];
        }
        return;
    }

    // ---- gemm1 role: one block = one (row-tile-group, ch) pair ----
    unsigned short* Wl = (unsigned short*)lsh;
    int g1 = blockIdx.x - NCHUNK;
    int rt = g1 >> 1;
    int ch = g1 & 1;          // column half: cols [ch*128, ch*128+128)
    int lane = tid & 63, wv = tid >> 6;
    int r0 = (rt * 4 + wv) * 16;
    int g = lane >> 4, q = lane & 15;

    int ar = min(r0 + q, NN - 1);
    const float* xr = x + (size_t)ar * FIN;
    bf16x8 afr[4];
    #pragma unroll
    for (int kt = 0; kt < 4; ++kt) {
        float4 u0 = *(const float4*)(xr + kt * 32 + g * 8);
        float4 u1 = *(const float4*)(xr + kt * 32 + g * 8 + 4);
        bf16x8 a;
        a[0] = (short)f2bf(u0.x); a[1] = (short)f2bf(u0.y);
        a[2] = (short)f2bf(u0.z); a[3] = (short)f2bf(u0.w);
        a[4] = (short)f2bf(u1.x); a[5] = (short)f2bf(u1.y);
        a[6] = (short)f2bf(u1.z); a[7] = (short)f2bf(u1.w);
        afr[kt] = a;
    }

    const uint4* src = (const uint4*)(W1t + (size_t)ch * 128 * FIN);
    #pragma unroll
    for (int i = 0; i < 8; ++i) {
        int idx = tid + i * 256;
        uint4 v = src[idx];
        unsigned byte = (unsigned)idx << 4;
        unsigned dst = byte ^ (((byte >> 8) & 7) << 4);
        *(uint4*)((char*)Wl + dst) = v;
    }
    __syncthreads();

    #pragma unroll
    for (int hh = 0; hh < 2; ++hh) {
        int h = ch * 2 + hh;
        float ps[4] = {0.f, 0.f, 0.f, 0.f};
        float pd[4] = {0.f, 0.f, 0.f, 0.f};
        #pragma unroll
        for (int tl = 0; tl < 4; ++tl) {
            int col = (h * 4 + tl) * 16 + q;
            int cl = col - ch * 128;
            f32x4 acc = {0.f, 0.f, 0.f, 0.f};
            #pragma unroll
            for (int kt = 0; kt < 4; ++kt) {
                unsigned bb = (unsigned)cl * 256 + kt * 64 + g * 16;
                bf16x8 b = *(const bf16x8*)((const char*)Wl + (bb ^ (((unsigned)cl & 7) << 4)));
                acc = __builtin_amdgcn_mfma_f32_16x16x32_bf16(afr[kt], b, acc, 0, 0, 0);
            }
            float av = asrc[col], bv = adst[col];
            #pragma unroll
            for (int j = 0; j < 4; ++j) {
                int rr = min(r0 + g * 4 + j, NN - 1);
                h1f[(size_t)rr * C1 + col] = f2fp8(acc[j]);
                ps[j] += acc[j] * av;
                pd[j] += acc[j] * bv;
            }
        }
        #pragma unroll
        for (int j = 0; j < 4; ++j) {
            #pragma unroll
            for (int off = 1; off < 16; off <<= 1) {
                ps[j] += __shfl_xor(ps[j], off);
                pd[j] += __shfl_xor(pd[j], off);
            }
            if (q == 0) {
                int rr = min(r0 + g * 4 + j, NN - 1);
                es1[rr * 4 + h] = ps[j];
                ed1[rr * 4 + h] = pd[j];
            }
        }
    }
}

// per-bucket: local degrees -> scan -> offs + colsrc fill (all XCD-local)
__global__ __launch_bounds__(1024) void k_bfill(const int* __restrict__ ebuf,
                                                const int* __restrict__ bhistp,
                                                int* __restrict__ offs,
                                                int* __restrict__ colsrc) {
    __shared__ int ldeg[1024];
    __shared__ int lcur[1024];
    __shared__ int ws[16];
    __shared__ int ssum[NBUK];
    __shared__ int sbase[NBUK];
    int b = blockIdx.x;
    int tid = threadIdx.x;
    int nbase = b << BSH;
    int ncnt = min(1024, NN - nbase);
    if (tid < NBUK) {
        const int* hp = bhistp + tid * NHIST;
        int s = 0;
        #pragma unroll 16
        for (int j = 0; j < NHIST; ++j) s += hp[j];
        ssum[tid] = s;
    }
    ldeg[tid] = 0;
    __syncthreads();
    if (tid < 64) {
        int v = (tid < NBUK) ? ssum[tid] : 0;
        int xs = v;
        #pragma unroll
        for (int off = 1; off < 64; off <<= 1) {
            int t = __shfl_up(xs, off);
            if (tid >= off) xs += t;
        }
        if (tid < NBUK) sbase[tid] = xs - v;   // exclusive
    }
    __syncthreads();
    int ebeg = sbase[b], eend = sbase[b] + ssum[b];
    for (int i = ebeg + tid; i < eend; i += 1024)
        atomicAdd(&ldeg[ebuf[i] >> 17], 1);
    __syncthreads();
    int v = (tid < ncnt) ? ldeg[tid] + 1 : 0;
    int lane = tid & 63, wv = tid >> 6;
    int x = v;
    #pragma unroll
    for (int off = 1; off < 64; off <<= 1) {
        int t = __shfl_up(x, off);
        if (lane >= off) x += t;
    }
    if (lane == 63) ws[wv] = x;
    __syncthreads();
    if (tid < 16) {
        int y = ws[tid];
        #pragma unroll
        for (int off = 1; off < 16; off <<= 1) {
            int t = __shfl_up(y, off);
            if (tid >= off) y += t;
        }
        ws[tid] = y;
    }
    __syncthreads();
    int base = wv ? ws[wv - 1] : 0;
    int excl = base + x - v;
    int gofs = ebeg + nbase + excl;
    if (tid < ncnt) {
        offs[nbase + tid] = gofs;
        lcur[tid] = gofs;
    }
    __syncthreads();
    for (int i = ebeg + tid; i < eend; i += 1024) {
        int pe = ebuf[i];
        int p = atomicAdd(&lcur[pe >> 17], 1);
        colsrc[p] = pe & 0x1FFFF;
    }
    __syncthreads();
    if (tid < ncnt) colsrc[lcur[tid]] = nbase + tid;   // self-loop at segment end
}

// ---------------- Layer 1 aggregation: fp8 gathers, 4-load interleave, fp8 h1p out ----------------
__global__ __launch_bounds__(512) void k_agg1(const int* __restrict__ offs,
                                              const int* __restrict__ colsrc,
                                              const unsigned char* __restrict__ h1f,
                                              const float* __restrict__ es1,
                                              const float* __restrict__ ed1,
                                              const float* __restrict__ b1,
                                              unsigned char* __restrict__ h1p8) {
    __shared__ int   sls[8][64];
    __shared__ float sla[8][64][4];
    int lane = threadIdx.x & 63, wv = threadIdx.x >> 6;
    int n = blockIdx.x * 8 + wv;
    if (n >= NN) return;
    int beg = offs[n], end = offs[n + 1], deg = end - beg;
    float4 edv = *(const float4*)(ed1 + n * 4);
    int half = lane >> 5, q5 = lane & 31;
    int hd = q5 >> 3;
    f32x2 acc2[4];
    #pragma unroll
    for (int j = 0; j < 4; ++j) acc2[j] = (f32x2){0.f, 0.f};

    if (deg <= 64) {
        int msrc = 0;
        float m0 = 0.f, m1 = 0.f, m2 = 0.f, m3 = 0.f;
        if (lane < deg) {
            msrc = colsrc[beg + lane];
            float4 ev = *(const float4*)(es1 + msrc * 4);
            m0 = __expf(lrelu(ev.x + edv.x));
            m1 = __expf(lrelu(ev.y + edv.y));
            m2 = __expf(lrelu(ev.z + edv.z));
            m3 = __expf(lrelu(ev.w + edv.w));
        }
        float s0 = m0, s1 = m1, s2 = m2, s3 = m3;
        #pragma unroll
        for (int off = 1; off < 64; off <<= 1) {
            s0 += __shfl_xor(s0, off);
            s1 += __shfl_xor(s1, off);
            s2 += __shfl_xor(s2, off);
            s3 += __shfl_xor(s3, off);
        }
        sls[wv][lane] = msrc;
        sla[wv][lane][0] = m0 * (1.f / s0);
        sla[wv][lane][1] = m1 * (1.f / s1);
        sla[wv][lane][2] = m2 * (1.f / s2);
        sla[wv][lane][3] = m3 * (1.f / s3);

        for (int i = 0; i < deg; i += 8) {
            int e0 = (i + half) & 63, e1 = (i + 2 + half) & 63, e2 = (i + 4 + half) & 63, e3 = (i + 6 + half) & 63;
            int   s0i = sls[wv][e0], s1i = sls[wv][e1], s2i = sls[wv][e2], s3i = sls[wv][e3];
            f32x2 a0 = (f32x2){sla[wv][e0][hd], sla[wv][e0][hd]};
            f32x2 a1 = (f32x2){sla[wv][e1][hd], sla[wv][e1][hd]};
            f32x2 a2 = (f32x2){sla[wv][e2][hd], sla[wv][e2][hd]};
            f32x2 a3 = (f32x2){sla[wv][e3][hd], sla[wv][e3][hd]};
            uint2 h0 = *(const uint2*)(h1f + (size_t)s0i * C1 + q5 * 8);
            uint2 h1 = *(const uint2*)(h1f + (size_t)s1i * C1 + q5 * 8);
            uint2 h2 = *(const uint2*)(h1f + (size_t)s2i * C1 + q5 * 8);
            uint2 h3 = *(const uint2*)(h1f + (size_t)s3i * C1 + q5 * 8);
            f32x2 p;
            p = __builtin_amdgcn_cvt_pk_f32_fp8(h0.x, false); acc2[0] += p * a0;
            p = __builtin_amdgcn_cvt_pk_f32_fp8(h0.x, true);  acc2[1] += p * a0;
            p = __builtin_amdgcn_cvt_pk_f32_fp8(h0.y, false); acc2[2] += p * a0;
            p = __builtin_amdgcn_cvt_pk_f32_fp8(h0.y, true);  acc2[3] += p * a0;
            p = __builtin_amdgcn_cvt_pk_f32_fp8(h1.x, false); acc2[0] += p * a1;
            p = __builtin_amdgcn_cvt_pk_f32_fp8(h1.x, true);  acc2[1] += p * a1;
            p = __builtin_amdgcn_cvt_pk_f32_fp8(h1.y, false); acc2[2] += p * a1;
            p = __builtin_amdgcn_cvt_pk_f32_fp8(h1.y, true);  acc2[3] += p * a1;
            p = __builtin_amdgcn_cvt_pk_f32_fp8(h2.x, false); acc2[0] += p * a2;
            p = __builtin_amdgcn_cvt_pk_f32_fp8(h2.x, true);  acc2[1] += p * a2;
            p = __builtin_amdgcn_cvt_pk_f32_fp8(h2.y, false); acc2[2] += p * a2;
            p = __builtin_amdgcn_cvt_pk_f32_fp8(h2.y, true);  acc2[3] += p * a2;
            p = __builtin_amdgcn_cvt_pk_f32_fp8(h3.x, false); acc2[0] += p * a3;
            p = __builtin_amdgcn_cvt_pk_f32_fp8(h3.x, true);  acc2[1] += p * a3;
            p = __builtin_amdgcn_cvt_pk_f32_fp8(h3.y, false); acc2[2] += p * a3;
            p = __builtin_amdgcn_cvt_pk_f32_fp8(h3.y, true);  acc2[3] += p * a3;
        }
    } else {
        float s0 = 0.f, s1 = 0.f, s2 = 0.f, s3 = 0.f;
        for (int i = beg + lane; i < end; i += 64) {
            int s = colsrc[i];
            float4 ev = *(const float4*)(es1 + s * 4);
            s0 += __expf(lrelu(ev.x + edv.x));
            s1 += __expf(lrelu(ev.y + edv.y));
            s2 += __expf(lrelu(ev.z + edv.z));
            s3 += __expf(lrelu(ev.w + edv.w));
        }
        #pragma unroll
        for (int off = 1; off < 64; off <<= 1) {
            s0 += __shfl_xor(s0, off);
            s1 += __shfl_xor(s1, off);
            s2 += __shfl_xor(s2, off);
            s3 += __shfl_xor(s3, off);
        }
        float rr = hd == 0 ? 1.f / s0 : hd == 1 ? 1.f / s1 : hd == 2 ? 1.f / s2 : 1.f / s3;
        float ed_h = hd == 0 ? edv.x : hd == 1 ? edv.y : hd == 2 ? edv.z : edv.w;
        for (int i = beg; i < end; i += 2) {
            int idx = i + half;
            if (idx < end) {
                int s = colsrc[idx];
                float eh = es1[s * 4 + hd] + ed_h;
                float av = __expf(lrelu(eh)) * rr;
                f32x2 a = (f32x2){av, av};
                uint2 hv = *(const uint2*)(h1f + (size_t)s * C1 + q5 * 8);
                f32x2 p;
                p = __builtin_amdgcn_cvt_pk_f32_fp8(hv.x, false); acc2[0] += p * a;
                p = __builtin_amdgcn_cvt_pk_f32_fp8(hv.x, true);  acc2[1] += p * a;
                p = __builtin_amdgcn_cvt_pk_f32_fp8(hv.y, false); acc2[2] += p * a;
                p = __builtin_amdgcn_cvt_pk_f32_fp8(hv.y, true);  acc2[3] += p * a;
            }
        }
    }

    float acc[8];
    #pragma unroll
    for (int j = 0; j < 4; ++j) { acc[2*j] = acc2[j][0]; acc[2*j+1] = acc2[j][1]; }
    #pragma unroll
    for (int j = 0; j < 8; ++j) acc[j] += __shfl_xor(acc[j], 32);

    if (half == 0) {
        float4 bv0 = *(const float4*)(b1 + q5 * 8);
        float4 bv1 = *(const float4*)(b1 + q5 * 8 + 4);
        float v0 = eluf(acc[0] + bv0.x), v1 = eluf(acc[1] + bv0.y);
        float v2 = eluf(acc[2] + bv0.z), v3 = eluf(acc[3] + bv0.w);
        float v4 = eluf(acc[4] + bv1.x), v5 = eluf(acc[5] + bv1.y);
        float v6 = eluf(acc[6] + bv1.z), v7 = eluf(acc[7] + bv1.w);
        int lo = __builtin_amdgcn_cvt_pk_fp8_f32(v0, v1, 0, false);
        lo = __builtin_amdgcn_cvt_pk_fp8_f32(v2, v3, lo, true);
        int hi = __builtin_amdgcn_cvt_pk_fp8_f32(v4, v5, 0, false);
        hi = __builtin_amdgcn_cvt_pk_fp8_f32(v6, v7, hi, true);
        uint2 o = make_uint2((unsigned)lo, (unsigned)hi);
        *(uint2*)(h1p8 + (size_t)n * C1 + q5 * 8) = o;
    }
}

// ---------------- Layer 2 GEMM (fp8 MFMA, LDS-staged fp8 W2, fp8 h2 output) ----------------
__global__ __launch_bounds__(256) void k_gemm2(const unsigned char* __restrict__ h1p8,
                                               const unsigned char* __restrict__ W2f,
                                               const float* __restrict__ as2,
                                               const float* __restrict__ ad2,
                                               unsigned char* __restrict__ h2f,
                                               float* __restrict__ es2,
                                               float* __restrict__ ed2) {
    __shared__ unsigned char Wl[HID * C1];   // 16 KB fp8
    int tid = threadIdx.x;
    int lane = tid & 63, wv = tid >> 6;
    int r0 = (blockIdx.x * 4 + wv) * 16;
    int g = lane >> 4, q = lane & 15;

    // stage 2048 x 8B, swizzle bits 3-5 by col (256B/col)
    const uint2* src = (const uint2*)W2f;
    #pragma unroll
    for (int i = 0; i < 8; ++i) {
        int idx = tid + i * 256;
        uint2 v = src[idx];
        unsigned byte = (unsigned)idx << 3;
        unsigned dst = byte ^ (((byte >> 8) & 7) << 3);
        *(uint2*)(Wl + dst) = v;
    }

    int ar = min(r0 + q, NN - 1);
    const unsigned char* arp = h1p8 + (size_t)ar * C1;
    long long afr[8];
    #pragma unroll
    for (int kt = 0; kt < 8; ++kt)
        afr[kt] = *(const long long*)(arp + kt * 32 + g * 8);

    __syncthreads();

    float ps[4] = {0.f, 0.f, 0.f, 0.f};
    float pd[4] = {0.f, 0.f, 0.f, 0.f};
    #pragma unroll
    for (int t = 0; t < 4; ++t) {
        int col = t * 16 + q;
        f32x4 acc = {0.f, 0.f, 0.f, 0.f};
        #pragma unroll
        for (int kt = 0; kt < 8; ++kt) {
            unsigned bb = (unsigned)col * 256 + kt * 32 + g * 8;
            long long b = *(const long long*)(Wl + (bb ^ (((unsigned)col & 7) << 3)));
            acc = __builtin_amdgcn_mfma_f32_16x16x32_fp8_fp8(afr[kt], b, acc, 0, 0, 0);
        }
        float av = as2[col], bv = ad2[col];
        #pragma unroll
        for (int j = 0; j < 4; ++j) {
            int rr = min(r0 + g * 4 + j, NN - 1);
            h2f[(size_t)rr * HID + col] = f2fp8(acc[j]);
            ps[j] += acc[j] * av;
            pd[j] += acc[j] * bv;
        }
    }
    #pragma unroll
    for (int j = 0; j < 4; ++j) {
        #pragma unroll
        for (int off = 1; off < 16; off <<= 1) {
            ps[j] += __shfl_xor(ps[j], off);
            pd[j] += __shfl_xor(pd[j], off);
        }
        if (q == 0) {
            int rr = min(r0 + g * 4 + j, NN - 1);
            es2[rr] = ps[j];
            ed2[rr] = pd[j];
        }
    }
}

// ---------------- Layer 2 aggregation: fp8 gathers, 4-load interleave, bf16 h3 ----------------
__global__ __launch_bounds__(512) void k_agg2(const int* __restrict__ offs,
                                              const int* __restrict__ colsrc,
                                              const unsigned char* __restrict__ h2f,
                                              const float* __restrict__ es2,
                                              const float* __restrict__ ed2,
                                              const float* __restrict__ b2,
                                              unsigned short* __restrict__ h3) {
    __shared__ int   sls[8][64];
    __shared__ float sla[8][64];
    int lane = threadIdx.x & 63, wv = threadIdx.x >> 6;
    int n = blockIdx.x * 8 + wv;
    if (n >= NN) return;
    int beg = offs[n], end = offs[n + 1], deg = end - beg;
    float edv = ed2[n];
    int g = lane >> 4, q = lane & 15;
    f32x2 acc2[2];
    acc2[0] = (f32x2){0.f, 0.f};
    acc2[1] = (f32x2){0.f, 0.f};

    if (deg <= 64) {
        int msrc = 0;
        float mex = 0.f;
        if (lane < deg) {
            msrc = colsrc[beg + lane];
            mex = __expf(lrelu(es2[msrc] + edv));
        }
        float ss = mex;
        #pragma unroll
        for (int off = 1; off < 64; off <<= 1) ss += __shfl_xor(ss, off);
        sls[wv][lane] = msrc;
        sla[wv][lane] = mex * (1.f / ss);

        for (int i = 0; i < deg; i += 16) {
            int e0 = (i + g) & 63, e1 = (i + 4 + g) & 63, e2 = (i + 8 + g) & 63, e3 = (i + 12 + g) & 63;
            int   s0i = sls[wv][e0], s1i = sls[wv][e1], s2i = sls[wv][e2], s3i = sls[wv][e3];
            f32x2 a0 = (f32x2){sla[wv][e0], sla[wv][e0]};
            f32x2 a1 = (f32x2){sla[wv][e1], sla[wv][e1]};
            f32x2 a2 = (f32x2){sla[wv][e2], sla[wv][e2]};
            f32x2 a3 = (f32x2){sla[wv][e3], sla[wv][e3]};
            unsigned w0 = *(const unsigned*)(h2f + (size_t)s0i * HID + q * 4);
            unsigned w1 = *(const unsigned*)(h2f + (size_t)s1i * HID + q * 4);
            unsigned w2 = *(const unsigned*)(h2f + (size_t)s2i * HID + q * 4);
            unsigned w3 = *(const unsigned*)(h2f + (size_t)s3i * HID + q * 4);
            f32x2 p;
            p = __builtin_amdgcn_cvt_pk_f32_fp8(w0, false); acc2[0] += p * a0;
            p = __builtin_amdgcn_cvt_pk_f32_fp8(w0, true);  acc2[1] += p * a0;
            p = __builtin_amdgcn_cvt_pk_f32_fp8(w1, false); acc2[0] += p * a1;
            p = __builtin_amdgcn_cvt_pk_f32_fp8(w1, true);  acc2[1] += p * a1;
            p = __builtin_amdgcn_cvt_pk_f32_fp8(w2, false); acc2[0] += p * a2;
            p = __builtin_amdgcn_cvt_pk_f32_fp8(w2, true);  acc2[1] += p * a2;
            p = __builtin_amdgcn_cvt_pk_f32_fp8(w3, false); acc2[0] += p * a3;
            p = __builtin_amdgcn_cvt_pk_f32_fp8(w3, true);  acc2[1] += p * a3;
        }
    } else {
        float ss = 0.f;
        for (int i = beg + lane; i < end; i += 64) {
            int s = colsrc[i];
            ss += __expf(lrelu(es2[s] + edv));
        }
        #pragma unroll
        for (int off = 1; off < 64; off <<= 1) ss += __shfl_xor(ss, off);
        float rs = 1.f / ss;
        for (int i = beg; i < end; i += 4) {
            int idx = i + g;
            if (idx < end) {
                int s = colsrc[idx];
                float av = __expf(lrelu(es2[s] + edv)) * rs;
                f32x2 a = (f32x2){av, av};
                unsigned w = *(const unsigned*)(h2f + (size_t)s * HID + q * 4);
                f32x2 p;
                p = __builtin_amdgcn_cvt_pk_f32_fp8(w, false); acc2[0] += p * a;
                p = __builtin_amdgcn_cvt_pk_f32_fp8(w, true);  acc2[1] += p * a;
            }
        }
    }

    float acc[4] = {acc2[0][0], acc2[0][1], acc2[1][0], acc2[1][1]};
    #pragma unroll
    for (int j = 0; j < 4; ++j) {
        acc[j] += __shfl_xor(acc[j], 16);
        acc[j] += __shfl_xor(acc[j], 32);
    }

    float v0 = __shfl(acc[0], lane >> 2);
    float v1 = __shfl(acc[1], lane >> 2);
    float v2 = __shfl(acc[2], lane >> 2);
    float v3 = __shfl(acc[3], lane >> 2);
    int jj = lane & 3;
    float o = jj == 0 ? v0 : jj == 1 ? v1 : jj == 2 ? v2 : v3;
    h3[(size_t)n * HID + lane] = f2bf(eluf(o + b2[lane]));
}

// ---------------- fused mean-pool + classifier (bf16 h3) ----------------
__global__ __launch_bounds__(256) void k_poolcls(const unsigned short* __restrict__ h3,
                                                 const int* __restrict__ gstart,
                                                 const float* __restrict__ Wc,
                                                 const float* __restrict__ bc,
                                                 float* __restrict__ out) {
    __shared__ float red[4][64];
    int g = blockIdx.x;
    int lane = threadIdx.x & 63, wv = threadIdx.x >> 6;
    int gs = gstart[g], ge = gstart[g + 1];
    float acc = 0.f;
    for (int r = gs + wv; r < ge; r += 4)
        acc += bf2f(h3[(size_t)r * HID + lane]);
    red[wv][lane] = acc;
    __syncthreads();
    if (wv == 0) {
        float p = red[0][lane] + red[1][lane] + red[2][lane] + red[3][lane];
        float c = fmaxf((float)(ge - gs), 1.f);
        p /= c;
        float s0 = p * Wc[lane * 2 + 0];
        float s1 = p * Wc[lane * 2 + 1];
        #pragma unroll
        for (int off = 1; off < 64; off <<= 1) {
            s0 += __shfl_xor(s0, off);
            s1 += __shfl_xor(s1, off);
        }
        if (lane == 0) {
            out[g * 2 + 0] = s0 + bc[0];
            out[g * 2 + 1] = s1 + bc[1];
        }
    }
}

extern "C" void kernel_launch(void* const* d_in, const int* in_sizes, int n_in,
                              void* d_out, int out_size, void* d_ws, size_t ws_size,
                              hipStream_t stream) {
    const float* x   = (const float*)d_in[0];
    const int* ei    = (const int*)d_in[1];
    const int* batch = (const int*)d_in[2];
    const float* W1  = (const float*)d_in[4];
    const float* as1 = (const float*)d_in[5];
    const float* ad1 = (const float*)d_in[6];
    const float* b1  = (const float*)d_in[7];
    const float* W2  = (const float*)d_in[8];
    const float* as2 = (const float*)d_in[9];
    const float* ad2 = (const float*)d_in[10];
    const float* b2  = (const float*)d_in[11];
    const float* Wc  = (const float*)d_in[12];
    const float* bc  = (const float*)d_in[13];
    float* out = (float*)d_out;

    char* p = (char*)d_ws;
    auto alloc = [&](size_t bytes) -> char* {
        char* r = p;
        p += (bytes + 255) & ~(size_t)255;
        return r;
    };
    int* offs    = (int*)alloc((NN + 1) * sizeof(int));
    int* colsrc  = (int*)alloc((size_t)ETOT * sizeof(int));
    int* ebuf    = (int*)alloc((size_t)NE * sizeof(int));   // packed dlocal<<17|src
    int* bhistp  = (int*)alloc(NBUK * NHIST * sizeof(int)); // partial histograms [NBUK][NHIST]
    int* bcur    = (int*)alloc(NBUK * sizeof(int));
    int* gstart  = (int*)alloc((NG + 1) * sizeof(int));
    unsigned short* W1t = (unsigned short*)alloc((size_t)FIN * C1 * sizeof(short));
    unsigned char* W2f  = (unsigned char*)alloc((size_t)C1 * HID);         // fp8 W2
    unsigned char* h1f  = (unsigned char*)alloc((size_t)NN * C1);          // fp8 h1
    unsigned char* h1p8 = (unsigned char*)alloc((size_t)NN * C1);          // fp8 h1'
    unsigned char* h2f  = (unsigned char*)alloc((size_t)NN * HID);         // fp8 h2
    float* es1   = (float*)alloc((size_t)NN * 4 * sizeof(float));
    float* ed1   = (float*)alloc((size_t)NN * 4 * sizeof(float));
    float* es2v  = (float*)alloc((size_t)NN * sizeof(float));
    float* ed2v  = (float*)alloc((size_t)NN * sizeof(float));
    unsigned short* h3 = (unsigned short*)alloc((size_t)NN * HID * sizeof(short));  // bf16

    const int* srcA = ei;       // edge_index[0]
    const int* dstA = ei + NE;  // edge_index[1]

    k_setup<<<NPREP + NHIST + 1, 256, 0, stream>>>(W1, W2, dstA, batch, W1t, W2f,
                                                   bhistp, bcur, offs, gstart);
    k_part_gemm1<<<NCHUNK + 2 * NGEMM1, 256, 0, stream>>>(srcA, dstA, bhistp, bcur, ebuf,
                                                          x, W1t, as1, ad1, h1f, es1, ed1);
    k_bfill<<<NBUK, 1024, 0, stream>>>(ebuf, bhistp, offs, colsrc);

    k_agg1<<<(NN + 7) / 8, 512, 0, stream>>>(offs, colsrc, h1f, es1, ed1, b1, h1p8);
    k_gemm2<<<(NN / 16 + 3) / 4, 256, 0, stream>>>(h1p8, W2f, as2, ad2, h2f, es2v, ed2v);
    k_agg2<<<(NN + 7) / 8, 512, 0, stream>>>(offs, colsrc, h2f, es2v, ed2v, b2, h3);
    k_poolcls<<<NG, 256, 0, stream>>>(h3, gstart, Wc, bc, out);
}